// Round 6
// baseline (2894.312 us; speedup 1.0000x reference)
//
#include <hip/hip_runtime.h>
#include <math.h>

// Problem constants
#define N_B     2
#define T_SEQ   2048
#define D_MODEL 1024
#define N_HEADS 16
#define D_HEAD  64
#define TOPK_N  64
#define DCAP    80    // definite-in capacity (provably <= 63)
#define ACAP    32    // ambiguous-band capacity (expected 1-3)
#define QROWS   8     // q-rows per block
#define RPW     2     // q-rows per wave

// laplace(x) = 0.5*(1+erf((x-mu)*sqrt(2/pi))), mu=sqrt(.5)
#define LAP_MU_F  0.70710678f
#define LAP_INV_F 0.79788456f
// certified |s32 - s64| bound (true ~1e-6 rms; 100x margin)
#define EERR      1e-4f

#define AS1 __attribute__((address_space(1)))
#define AS3 __attribute__((address_space(3)))

typedef _Float16 f16x4 __attribute__((ext_vector_type(4)));
typedef _Float16 f16x8 __attribute__((ext_vector_type(8)));
typedef float    f32x4 __attribute__((ext_vector_type(4)));

// decode monotone key back to float
__device__ __forceinline__ float key2f(unsigned k) {
  unsigned b = (k & 0x80000000u) ? (k & 0x7fffffffu) : ~k;
  return __uint_as_float(b);
}

// ---------------------------------------------------------------------------
// mask bit-pack: bits[row][lane] bit j = (mask[row][j*64+lane] != 0)
// Layout matches the score-register layout s[j] on lane `lane` exactly.
// ---------------------------------------------------------------------------
__global__ __launch_bounds__(256)
void pack_mask(const int* __restrict__ mask, unsigned* __restrict__ bits)
{
  const int wv = threadIdx.x >> 6, lane = threadIdx.x & 63;
  const int row = blockIdx.x * 4 + wv;             // 0 .. N_B*T_SEQ-1
  const int* mrow = mask + (size_t)row * T_SEQ;
  unsigned w = 0;
#pragma unroll
  for (int j = 0; j < 32; ++j)
    w |= (mrow[j * 64 + lane] != 0 ? 1u : 0u) << j;
  bits[(size_t)row * 64 + lane] = w;
}

// ---------------------------------------------------------------------------
// f16-split MFMA GEMM: out = A @ W^T + bias (validated round 5; bf16-ulp exact)
// ---------------------------------------------------------------------------
__global__ __launch_bounds__(256)
void gemm_mfma_f16s(const float* __restrict__ A, const float* __restrict__ W,
                    const float* __restrict__ bias, float* __restrict__ out,
                    int M, int N, int Kd, int head_layout)
{
  __shared__ _Float16 Ah[64][72], Al[64][72], Bh[64][72], Bl[64][72]; // 36 KB

  const int t = threadIdx.x, lane = t & 63, wv = t >> 6;
  const int row0 = blockIdx.x * 64, col0 = blockIdx.y * 64;
  const int wr = (wv >> 1) * 32, wc = (wv & 1) * 32;
  f32x4 acc[2][2] = {};

  for (int k0 = 0; k0 < Kd; k0 += 64) {
#pragma unroll
    for (int jj = 0; jj < 4; ++jj) {
      int f = t + jj * 256;                 // 0..1023 float4s
      int r = f >> 4, kq = f & 15;
      float4 va = *reinterpret_cast<const float4*>(&A[(size_t)(row0 + r) * Kd + k0 + kq * 4]);
      f16x4 h, l;
      h[0] = (_Float16)va.x; l[0] = (_Float16)(va.x - (float)h[0]);
      h[1] = (_Float16)va.y; l[1] = (_Float16)(va.y - (float)h[1]);
      h[2] = (_Float16)va.z; l[2] = (_Float16)(va.z - (float)h[2]);
      h[3] = (_Float16)va.w; l[3] = (_Float16)(va.w - (float)h[3]);
      *reinterpret_cast<f16x4*>(&Ah[r][kq * 4]) = h;
      *reinterpret_cast<f16x4*>(&Al[r][kq * 4]) = l;
      float4 vw = *reinterpret_cast<const float4*>(&W[(size_t)(col0 + r) * Kd + k0 + kq * 4]);
      vw.x *= 64.f; vw.y *= 64.f; vw.z *= 64.f; vw.w *= 64.f;
      h[0] = (_Float16)vw.x; l[0] = (_Float16)(vw.x - (float)h[0]);
      h[1] = (_Float16)vw.y; l[1] = (_Float16)(vw.y - (float)h[1]);
      h[2] = (_Float16)vw.z; l[2] = (_Float16)(vw.z - (float)h[2]);
      h[3] = (_Float16)vw.w; l[3] = (_Float16)(vw.w - (float)h[3]);
      *reinterpret_cast<f16x4*>(&Bh[r][kq * 4]) = h;
      *reinterpret_cast<f16x4*>(&Bl[r][kq * 4]) = l;
    }
    __syncthreads();

#pragma unroll
    for (int ks = 0; ks < 2; ++ks) {
      const int koff = ks * 32 + (lane >> 4) * 8;
      f16x8 a_h[2], a_l[2], b_h[2], b_l[2];
#pragma unroll
      for (int i = 0; i < 2; ++i) {
        int ar = wr + i * 16 + (lane & 15);
        a_h[i] = *reinterpret_cast<const f16x8*>(&Ah[ar][koff]);
        a_l[i] = *reinterpret_cast<const f16x8*>(&Al[ar][koff]);
        int bc = wc + i * 16 + (lane & 15);
        b_h[i] = *reinterpret_cast<const f16x8*>(&Bh[bc][koff]);
        b_l[i] = *reinterpret_cast<const f16x8*>(&Bl[bc][koff]);
      }
#pragma unroll
      for (int i = 0; i < 2; ++i)
#pragma unroll
        for (int j = 0; j < 2; ++j) {
          acc[i][j] = __builtin_amdgcn_mfma_f32_16x16x32_f16(a_h[i], b_h[j], acc[i][j], 0, 0, 0);
          acc[i][j] = __builtin_amdgcn_mfma_f32_16x16x32_f16(a_l[i], b_h[j], acc[i][j], 0, 0, 0);
          acc[i][j] = __builtin_amdgcn_mfma_f32_16x16x32_f16(a_h[i], b_l[j], acc[i][j], 0, 0, 0);
        }
    }
    __syncthreads();
  }

#pragma unroll
  for (int i = 0; i < 2; ++i)
#pragma unroll
    for (int j = 0; j < 2; ++j)
#pragma unroll
      for (int r = 0; r < 4; ++r) {
        int row = row0 + wr + i * 16 + ((lane >> 4) & 3) * 4 + r;
        int col = col0 + wc + j * 16 + (lane & 15);
        float v = acc[i][j][r] * 0.015625f + bias[col];   // /64 (exact)
        if (head_layout) {
          int b = row >> 11, tt = row & (T_SEQ - 1);
          int hh = col >> 6, dk = col & 63;
          out[(((size_t)b * N_HEADS + hh) * T_SEQ + tt) * D_HEAD + dk] = v;
        } else {
          out[(size_t)row * N + col] = v;
        }
      }
}

// ---------------------------------------------------------------------------
// fp64 GEMM (head layout) for Q,K; optionally writes an fp32 copy.
// ---------------------------------------------------------------------------
__global__ __launch_bounds__(256)
void gemm_f64_head(const float* __restrict__ A, const float* __restrict__ W,
                   const float* __restrict__ bias, double* __restrict__ out,
                   float* __restrict__ out32, int Kd)
{
  __shared__ double As[64][33];
  __shared__ double Ws[64][33];
  const int t = threadIdx.x;
  const int row0 = blockIdx.x * 64, col0 = blockIdx.y * 64;
  const int ty = t >> 4, tx = t & 15;
  double acc[4][4] = {{0.0}};

  for (int k0 = 0; k0 < Kd; k0 += 32) {
#pragma unroll
    for (int jj = 0; jj < 2; ++jj) {
      int idx = t + jj * 256;
      int r = idx >> 3, kq = idx & 7;
      float4 va = *reinterpret_cast<const float4*>(&A[(size_t)(row0 + r) * Kd + k0 + kq * 4]);
      As[r][kq*4+0] = (double)va.x; As[r][kq*4+1] = (double)va.y;
      As[r][kq*4+2] = (double)va.z; As[r][kq*4+3] = (double)va.w;
      float4 vw = *reinterpret_cast<const float4*>(&W[(size_t)(col0 + r) * Kd + k0 + kq * 4]);
      Ws[r][kq*4+0] = (double)vw.x; Ws[r][kq*4+1] = (double)vw.y;
      Ws[r][kq*4+2] = (double)vw.z; Ws[r][kq*4+3] = (double)vw.w;
    }
    __syncthreads();
#pragma unroll
    for (int kk = 0; kk < 32; ++kk) {
      double a[4], b[4];
#pragma unroll
      for (int i = 0; i < 4; ++i) a[i] = As[ty + 16*i][kk];
#pragma unroll
      for (int j = 0; j < 4; ++j) b[j] = Ws[tx + 16*j][kk];
#pragma unroll
      for (int i = 0; i < 4; ++i)
#pragma unroll
        for (int j = 0; j < 4; ++j) acc[i][j] = fma(a[i], b[j], acc[i][j]);
    }
    __syncthreads();
  }

#pragma unroll
  for (int i = 0; i < 4; ++i)
#pragma unroll
    for (int j = 0; j < 4; ++j) {
      int r = row0 + ty + 16*i, o = col0 + tx + 16*j;
      double v = acc[i][j] + (double)bias[o];
      int b = r >> 11, tt = r & (T_SEQ - 1);
      int h = o >> 6, dk = o & 63;
      size_t oi = (((size_t)b * N_HEADS + h) * T_SEQ + tt) * D_HEAD + dk;
      out[oi] = v;
      if (out32) out32[oi] = (float)v;
    }
}

// ---------------------------------------------------------------------------
// Per-row tail with certified bands (round-4/5 logic; mask via bitword).
// ---------------------------------------------------------------------------
__device__ __forceinline__ void process_row(
    const float (&s)[32], int* __restrict__ dkl, float* __restrict__ dwl,
    int* __restrict__ akl, float* __restrict__ awl,
    const double* __restrict__ q64, const double* __restrict__ Kd,
    const float* __restrict__ V, unsigned mw, const int* __restrict__ mask,
    int use_bits, float* __restrict__ X,
    size_t kvbase, size_t mbase, size_t xbase, int lane)
{
  // exact fp32 64th-largest to 256-ulp resolution (mono-key bit search)
  unsigned p = 0u;
  for (int bit = 31; bit >= 8; --bit) {
    unsigned cand = p | (1u << bit);
    float cf = key2f(cand);
    int cnt = 0;
#pragma unroll
    for (int j = 0; j < 32; ++j) cnt += (int)__popcll(__ballot(s[j] >= cf));
    if (cnt >= TOPK_N) p = cand;
  }
  const float pv = key2f(p);          // pv <= v32
  const float pn = key2f(p + 256u);   // v32 < pn
  const float hi = pn + 2.f * EERR;   // s32>=hi  => certainly in f64 top-64
  const float lo = pv - 2.f * EERR;   // s32<lo   => certainly out

  // compact definite list (with weights) and ambiguous list
  int m = 0, na = 0;
#pragma unroll
  for (int j = 0; j < 32; ++j) {
    float sv = s[j];
    bool isd = (sv >= hi);
    bool isa = (sv >= lo) && !isd;
    unsigned long long bd = __ballot(isd);
    unsigned long long ba = __ballot(isa);
    int k = j * 64 + lane;
    if (isd) {
      int pos = m + (int)__popcll(bd & ((1ull << lane) - 1ull));
      if (pos < DCAP) {
        bool msk = use_bits ? (((mw >> j) & 1u) != 0u) : (mask[mbase + k] != 0);
        dkl[pos] = k;
        dwl[pos] = msk ? 0.f : 0.5f * (1.f + erff((sv - LAP_MU_F) * LAP_INV_F));
      }
    }
    if (isa) {
      int pos = na + (int)__popcll(ba & ((1ull << lane) - 1ull));
      if (pos < ACAP) akl[pos] = k;
    }
    m += (int)__popcll(bd);
    na += (int)__popcll(ba);
  }
  if (m > DCAP) m = DCAP;
  if (na > ACAP) na = ACAP;
  const int need = TOPK_N - m;

  // lane-parallel f64 refine of ambiguous candidates (lane e owns akl[e])
  int ke = akl[lane < na ? lane : 0];
  const double* kr = &Kd[kvbase + (size_t)ke * D_HEAD];
  double a0 = 0, a1 = 0, a2 = 0, a3 = 0;
#pragma unroll
  for (int d = 0; d < 64; d += 4) {
    a0 = fma(q64[d + 0], kr[d + 0], a0);
    a1 = fma(q64[d + 1], kr[d + 1], a1);
    a2 = fma(q64[d + 2], kr[d + 2], a2);
    a3 = fma(q64[d + 3], kr[d + 3], a3);
  }
  double s64e = ((a0 + a1) + (a2 + a3)) * 0.125;

  // mask bit for own ambiguous candidate (cross-lane word fetch)
  unsigned mwk = __shfl(mw, ke & 63);
  bool mska = use_bits ? (((mwk >> (ke >> 6)) & 1u) != 0u)
                       : (lane < na ? (mask[mbase + ke] != 0) : false);

  // rank among A by exact f64 (strict >): rank<need <=> s64 >= vk (ties kept)
  int rank = 0;
  for (int i = 0; i < na; ++i) {
    double vi = __shfl(s64e, i);
    rank += (vi > s64e) ? 1 : 0;
  }
  if (lane < na) {
    bool keep = (rank < need) && !mska;
    awl[lane] = keep ? 0.5f * (1.f + erff(((float)s64e - LAP_MU_F) * LAP_INV_F)) : 0.f;
  }

  // PV: lane owns output dim d=lane
  float acc = 0.f;
  for (int e = 0; e < m; ++e)
    acc = fmaf(dwl[e], V[kvbase + (size_t)dkl[e] * D_HEAD + lane], acc);
  for (int e = 0; e < na; ++e)
    acc = fmaf(awl[e], V[kvbase + (size_t)akl[e] * D_HEAD + lane], acc);
  X[xbase + lane] = acc;
}

// ---------------------------------------------------------------------------
// Fused attention. Block = 256 threads = 4 waves, QROWS=8 (2 rows/wave).
// K staged via global_load_lds with BOTH-SIDES slot swizzle:
//   LDS slot (r, s) holds logical quad s ^ ((r>>1)&3)  (pre-swizzled source);
//   read slot j ^ ((r>>1)&3) yields logical quad j — uniform bank coverage.
// ---------------------------------------------------------------------------
__global__ __launch_bounds__(256)
void attn_fused(const double* __restrict__ Qd, const double* __restrict__ Kd,
                const float* __restrict__ K32, const float* __restrict__ V,
                const int* __restrict__ mask, const unsigned* __restrict__ mbits,
                int use_bits, float* __restrict__ X)
{
  __shared__ float  KsL[512 * 16];       // 32 KB swizzled K chunk
  __shared__ double q8d[QROWS][64];      // 4 KB
  __shared__ int    dk_l[QROWS][DCAP];
  __shared__ float  dw_l[QROWS][DCAP];
  __shared__ int    ak_l[QROWS][ACAP];
  __shared__ float  aw_l[QROWS][ACAP];

  const int t = threadIdx.x, wv = t >> 6, lane = t & 63;
  const int bh = blockIdx.y, b = bh >> 4, h = bh & 15;
  const int q0 = blockIdx.x * QROWS;
  const size_t kvbase = (size_t)bh * T_SEQ * D_HEAD;

  for (int i = t; i < QROWS * 64; i += 256) {
    int r = i >> 6, d = i & 63;
    q8d[r][d] = Qd[kvbase + (size_t)(q0 + r) * D_HEAD + d];
  }
  __syncthreads();

  const int r0 = wv * RPW;
  float s0[32], s1[32];
#pragma unroll
  for (int j = 0; j < 32; ++j) { s0[j] = 0.f; s1[j] = 0.f; }

  for (int db = 0; db < 4; ++db) {
    float4 qa[4], qb[4];
#pragma unroll
    for (int qq = 0; qq < 4; ++qq) {
      qa[qq] = make_float4((float)q8d[r0][db*16+qq*4+0], (float)q8d[r0][db*16+qq*4+1],
                           (float)q8d[r0][db*16+qq*4+2], (float)q8d[r0][db*16+qq*4+3]);
      qb[qq] = make_float4((float)q8d[r0+1][db*16+qq*4+0], (float)q8d[r0+1][db*16+qq*4+1],
                           (float)q8d[r0+1][db*16+qq*4+2], (float)q8d[r0+1][db*16+qq*4+3]);
    }
    for (int kc = 0; kc < 4; ++kc) {
      // stage 512 rows x 16 dims; dest linear, source pre-swizzled:
      // LDS slot (r, s) <- logical quad s ^ ((r>>1)&3)
#pragma unroll
      for (int jj = 0; jj < 8; ++jj) {
        int idx = t + jj * 256;
        int r = idx >> 2, s = idx & 3;
        int dq = s ^ ((r >> 1) & 3);
        const float* gp = &K32[kvbase + (size_t)(kc * 512 + r) * D_HEAD + db * 16 + dq * 4];
        char* lp = (char*)KsL + (size_t)(wv * 64 + jj * 256) * 16;
        __builtin_amdgcn_global_load_lds((const AS1 void*)gp, (AS3 void*)lp, 16, 0, 0);
      }
      __syncthreads();
#pragma unroll
      for (int i = 0; i < 8; ++i) {
        int kr2 = i * 64 + lane;
        int sw = (kr2 >> 1) & 3;
        const float* kp = &KsL[kr2 * 16];
        float4 k0 = *reinterpret_cast<const float4*>(&kp[(0 ^ sw) * 4]);
        float4 k1 = *reinterpret_cast<const float4*>(&kp[(1 ^ sw) * 4]);
        float4 k2 = *reinterpret_cast<const float4*>(&kp[(2 ^ sw) * 4]);
        float4 k3 = *reinterpret_cast<const float4*>(&kp[(3 ^ sw) * 4]);
        int j = kc * 8 + i;
        float a = s0[j], c = s1[j];
        a = fmaf(k0.x, qa[0].x, a); a = fmaf(k0.y, qa[0].y, a);
        a = fmaf(k0.z, qa[0].z, a); a = fmaf(k0.w, qa[0].w, a);
        a = fmaf(k1.x, qa[1].x, a); a = fmaf(k1.y, qa[1].y, a);
        a = fmaf(k1.z, qa[1].z, a); a = fmaf(k1.w, qa[1].w, a);
        a = fmaf(k2.x, qa[2].x, a); a = fmaf(k2.y, qa[2].y, a);
        a = fmaf(k2.z, qa[2].z, a); a = fmaf(k2.w, qa[2].w, a);
        a = fmaf(k3.x, qa[3].x, a); a = fmaf(k3.y, qa[3].y, a);
        a = fmaf(k3.z, qa[3].z, a); a = fmaf(k3.w, qa[3].w, a);
        c = fmaf(k0.x, qb[0].x, c); c = fmaf(k0.y, qb[0].y, c);
        c = fmaf(k0.z, qb[0].z, c); c = fmaf(k0.w, qb[0].w, c);
        c = fmaf(k1.x, qb[1].x, c); c = fmaf(k1.y, qb[1].y, c);
        c = fmaf(k1.z, qb[1].z, c); c = fmaf(k1.w, qb[1].w, c);
        c = fmaf(k2.x, qb[2].x, c); c = fmaf(k2.y, qb[2].y, c);
        c = fmaf(k2.z, qb[2].z, c); c = fmaf(k2.w, qb[2].w, c);
        c = fmaf(k3.x, qb[3].x, c); c = fmaf(k3.y, qb[3].y, c);
        c = fmaf(k3.z, qb[3].z, c); c = fmaf(k3.w, qb[3].w, c);
        s0[j] = a; s1[j] = c;
      }
      __syncthreads();
    }
  }
#pragma unroll
  for (int j = 0; j < 32; ++j) { s0[j] *= 0.125f; s1[j] *= 0.125f; }

  // wave-private tails
  {
    const int lr = r0, qg = q0 + lr;
    const size_t rowg = (size_t)b * T_SEQ + qg;
    unsigned mw = use_bits ? mbits[rowg * 64 + lane] : 0u;
    process_row(s0, dk_l[lr], dw_l[lr], ak_l[lr], aw_l[lr], q8d[lr],
                Kd, V, mw, mask, use_bits, X, kvbase,
                rowg * T_SEQ, rowg * D_MODEL + (size_t)h * D_HEAD, lane);
  }
  {
    const int lr = r0 + 1, qg = q0 + lr;
    const size_t rowg = (size_t)b * T_SEQ + qg;
    unsigned mw = use_bits ? mbits[rowg * 64 + lane] : 0u;
    process_row(s1, dk_l[lr], dw_l[lr], ak_l[lr], aw_l[lr], q8d[lr],
                Kd, V, mw, mask, use_bits, X, kvbase,
                rowg * T_SEQ, rowg * D_MODEL + (size_t)h * D_HEAD, lane);
  }
}

// ---------------------------------------------------------------------------
extern "C" void kernel_launch(void* const* d_in, const int* in_sizes, int n_in,
                              void* d_out, int out_size, void* d_ws, size_t ws_size,
                              hipStream_t stream)
{
  const float* query = (const float*)d_in[0];
  const float* key_  = (const float*)d_in[1];
  const float* value = (const float*)d_in[2];
  const int*   mask  = (const int*)d_in[3];
  const float* wq = (const float*)d_in[4];
  const float* bq = (const float*)d_in[5];
  const float* wk = (const float*)d_in[6];
  const float* bk = (const float*)d_in[7];
  const float* wvp = (const float*)d_in[8];
  const float* bv = (const float*)d_in[9];
  const float* wo = (const float*)d_in[10];
  const float* bo = (const float*)d_in[11];
  float* out = (float*)d_out;

  // ws: Qd f64 32M | Kd f64 32M | Ks32 f32 16M | Xb f32 16M | [mbits 1M if room]
  double* Qd   = (double*)d_ws;
  double* Kd   = (double*)((char*)d_ws + ((size_t)32 << 20));
  float*  Ks32 = (float*) ((char*)d_ws + ((size_t)64 << 20));
  float*  Xb   = (float*) ((char*)d_ws + ((size_t)80 << 20));
  float*  Vb   = out;   // V-projection parks in d_out; final GEMM overwrites it

  unsigned* mbits = nullptr;
  int use_bits = 0;
  if (ws_size >= ((size_t)97 << 20)) {
    mbits = (unsigned*)((char*)d_ws + ((size_t)96 << 20));
    use_bits = 1;
  }

  const int M = N_B * T_SEQ;   // 4096
  if (use_bits)
    hipLaunchKernelGGL(pack_mask, dim3(M / 4), dim3(256), 0, stream, mask, mbits);

  dim3 gg(M / 64, D_MODEL / 64), bb(256);
  hipLaunchKernelGGL(gemm_f64_head, gg, bb, 0, stream, query, wq, bq, Qd, (float*)nullptr, D_MODEL);
  hipLaunchKernelGGL(gemm_f64_head, gg, bb, 0, stream, key_,  wk, bk, Kd, Ks32, D_MODEL);
  hipLaunchKernelGGL(gemm_mfma_f16s, gg, bb, 0, stream, value, wvp, bv, Vb, M, D_MODEL, D_MODEL, 1);

  dim3 ga(T_SEQ / QROWS, N_B * N_HEADS);
  hipLaunchKernelGGL(attn_fused, ga, dim3(256), 0, stream, Qd, Kd, Ks32, Vb, mask, mbits, use_bits, Xb);

  hipLaunchKernelGGL(gemm_mfma_f16s, gg, bb, 0, stream, Xb, wo, bo, out, M, D_MODEL, D_MODEL, 0);
}

// Round 8
// 1887.498 us; speedup vs baseline: 1.5334x; 1.5334x over previous
//
#include <hip/hip_runtime.h>
#include <math.h>

// Problem constants
#define N_B     2
#define T_SEQ   2048
#define D_MODEL 1024
#define N_HEADS 16
#define D_HEAD  64
#define TOPK_N  64
#define DCAP    80    // definite-in capacity (provably <= 63)
#define ACAP    32    // ambiguous-band capacity (expected 1-3)
#define QROWS   8     // q-rows per block
#define RPW     2     // q-rows per wave

// laplace(x) = 0.5*(1+erf((x-mu)*sqrt(2/pi))), mu=sqrt(.5)
#define LAP_MU_F  0.70710678f
#define LAP_INV_F 0.79788456f
// certified |s32 - s64| bound (true ~1e-6 rms; 100x margin)
#define EERR      1e-4f

#define AS1 __attribute__((address_space(1)))
#define AS3 __attribute__((address_space(3)))

typedef _Float16 f16x4 __attribute__((ext_vector_type(4)));
typedef _Float16 f16x8 __attribute__((ext_vector_type(8)));
typedef float    f32x4 __attribute__((ext_vector_type(4)));

// decode monotone key back to float
__device__ __forceinline__ float key2f(unsigned k) {
  unsigned b = (k & 0x80000000u) ? (k & 0x7fffffffu) : ~k;
  return __uint_as_float(b);
}

// ---------------------------------------------------------------------------
// mask bit-pack: bits[row][lane] bit j = (mask[row][j*64+lane] != 0)
// ---------------------------------------------------------------------------
__global__ __launch_bounds__(256)
void pack_mask(const int* __restrict__ mask, unsigned* __restrict__ bits)
{
  const int wv = threadIdx.x >> 6, lane = threadIdx.x & 63;
  const int row = blockIdx.x * 4 + wv;             // 0 .. N_B*T_SEQ-1
  const int* mrow = mask + (size_t)row * T_SEQ;
  unsigned w = 0;
#pragma unroll
  for (int j = 0; j < 32; ++j)
    w |= (mrow[j * 64 + lane] != 0 ? 1u : 0u) << j;
  bits[(size_t)row * 64 + lane] = w;
}

// ---------------------------------------------------------------------------
// f16-split MFMA GEMM: out = A @ W^T + bias (validated; bf16-ulp exact)
// ---------------------------------------------------------------------------
__global__ __launch_bounds__(256)
void gemm_mfma_f16s(const float* __restrict__ A, const float* __restrict__ W,
                    const float* __restrict__ bias, float* __restrict__ out,
                    int M, int N, int Kd, int head_layout)
{
  __shared__ _Float16 Ah[64][72], Al[64][72], Bh[64][72], Bl[64][72]; // 36 KB

  const int t = threadIdx.x, lane = t & 63, wv = t >> 6;
  const int row0 = blockIdx.x * 64, col0 = blockIdx.y * 64;
  const int wr = (wv >> 1) * 32, wc = (wv & 1) * 32;
  f32x4 acc[2][2] = {};

  for (int k0 = 0; k0 < Kd; k0 += 64) {
#pragma unroll
    for (int jj = 0; jj < 4; ++jj) {
      int f = t + jj * 256;                 // 0..1023 float4s
      int r = f >> 4, kq = f & 15;
      float4 va = *reinterpret_cast<const float4*>(&A[(size_t)(row0 + r) * Kd + k0 + kq * 4]);
      f16x4 h, l;
      h[0] = (_Float16)va.x; l[0] = (_Float16)(va.x - (float)h[0]);
      h[1] = (_Float16)va.y; l[1] = (_Float16)(va.y - (float)h[1]);
      h[2] = (_Float16)va.z; l[2] = (_Float16)(va.z - (float)h[2]);
      h[3] = (_Float16)va.w; l[3] = (_Float16)(va.w - (float)h[3]);
      *reinterpret_cast<f16x4*>(&Ah[r][kq * 4]) = h;
      *reinterpret_cast<f16x4*>(&Al[r][kq * 4]) = l;
      float4 vw = *reinterpret_cast<const float4*>(&W[(size_t)(col0 + r) * Kd + k0 + kq * 4]);
      vw.x *= 64.f; vw.y *= 64.f; vw.z *= 64.f; vw.w *= 64.f;
      h[0] = (_Float16)vw.x; l[0] = (_Float16)(vw.x - (float)h[0]);
      h[1] = (_Float16)vw.y; l[1] = (_Float16)(vw.y - (float)h[1]);
      h[2] = (_Float16)vw.z; l[2] = (_Float16)(vw.z - (float)h[2]);
      h[3] = (_Float16)vw.w; l[3] = (_Float16)(vw.w - (float)h[3]);
      *reinterpret_cast<f16x4*>(&Bh[r][kq * 4]) = h;
      *reinterpret_cast<f16x4*>(&Bl[r][kq * 4]) = l;
    }
    __syncthreads();

#pragma unroll
    for (int ks = 0; ks < 2; ++ks) {
      const int koff = ks * 32 + (lane >> 4) * 8;
      f16x8 a_h[2], a_l[2], b_h[2], b_l[2];
#pragma unroll
      for (int i = 0; i < 2; ++i) {
        int ar = wr + i * 16 + (lane & 15);
        a_h[i] = *reinterpret_cast<const f16x8*>(&Ah[ar][koff]);
        a_l[i] = *reinterpret_cast<const f16x8*>(&Al[ar][koff]);
        int bc = wc + i * 16 + (lane & 15);
        b_h[i] = *reinterpret_cast<const f16x8*>(&Bh[bc][koff]);
        b_l[i] = *reinterpret_cast<const f16x8*>(&Bl[bc][koff]);
      }
#pragma unroll
      for (int i = 0; i < 2; ++i)
#pragma unroll
        for (int j = 0; j < 2; ++j) {
          acc[i][j] = __builtin_amdgcn_mfma_f32_16x16x32_f16(a_h[i], b_h[j], acc[i][j], 0, 0, 0);
          acc[i][j] = __builtin_amdgcn_mfma_f32_16x16x32_f16(a_l[i], b_h[j], acc[i][j], 0, 0, 0);
          acc[i][j] = __builtin_amdgcn_mfma_f32_16x16x32_f16(a_h[i], b_l[j], acc[i][j], 0, 0, 0);
        }
    }
    __syncthreads();
  }

#pragma unroll
  for (int i = 0; i < 2; ++i)
#pragma unroll
    for (int j = 0; j < 2; ++j)
#pragma unroll
      for (int r = 0; r < 4; ++r) {
        int row = row0 + wr + i * 16 + ((lane >> 4) & 3) * 4 + r;
        int col = col0 + wc + j * 16 + (lane & 15);
        float v = acc[i][j][r] * 0.015625f + bias[col];   // /64 (exact)
        if (head_layout) {
          int b = row >> 11, tt = row & (T_SEQ - 1);
          int hh = col >> 6, dk = col & 63;
          out[(((size_t)b * N_HEADS + hh) * T_SEQ + tt) * D_HEAD + dk] = v;
        } else {
          out[(size_t)row * N + col] = v;
        }
      }
}

// ---------------------------------------------------------------------------
// fp64 GEMM (head layout) for Q,K; optionally writes an fp32 copy.
// (Proven round-2/5/6 kernel — f64 VALU; CDNA4 f64 MFMA peak ~= VALU peak,
//  so the MFMA port offers little and its lane layout failed verification.)
// ---------------------------------------------------------------------------
__global__ __launch_bounds__(256)
void gemm_f64_head(const float* __restrict__ A, const float* __restrict__ W,
                   const float* __restrict__ bias, double* __restrict__ out,
                   float* __restrict__ out32, int Kd)
{
  __shared__ double As[64][33];
  __shared__ double Ws[64][33];
  const int t = threadIdx.x;
  const int row0 = blockIdx.x * 64, col0 = blockIdx.y * 64;
  const int ty = t >> 4, tx = t & 15;
  double acc[4][4] = {{0.0}};

  for (int k0 = 0; k0 < Kd; k0 += 32) {
#pragma unroll
    for (int jj = 0; jj < 2; ++jj) {
      int idx = t + jj * 256;
      int r = idx >> 3, kq = idx & 7;
      float4 va = *reinterpret_cast<const float4*>(&A[(size_t)(row0 + r) * Kd + k0 + kq * 4]);
      As[r][kq*4+0] = (double)va.x; As[r][kq*4+1] = (double)va.y;
      As[r][kq*4+2] = (double)va.z; As[r][kq*4+3] = (double)va.w;
      float4 vw = *reinterpret_cast<const float4*>(&W[(size_t)(col0 + r) * Kd + k0 + kq * 4]);
      Ws[r][kq*4+0] = (double)vw.x; Ws[r][kq*4+1] = (double)vw.y;
      Ws[r][kq*4+2] = (double)vw.z; Ws[r][kq*4+3] = (double)vw.w;
    }
    __syncthreads();
#pragma unroll
    for (int kk = 0; kk < 32; ++kk) {
      double a[4], b[4];
#pragma unroll
      for (int i = 0; i < 4; ++i) a[i] = As[ty + 16*i][kk];
#pragma unroll
      for (int j = 0; j < 4; ++j) b[j] = Ws[tx + 16*j][kk];
#pragma unroll
      for (int i = 0; i < 4; ++i)
#pragma unroll
        for (int j = 0; j < 4; ++j) acc[i][j] = fma(a[i], b[j], acc[i][j]);
    }
    __syncthreads();
  }

#pragma unroll
  for (int i = 0; i < 4; ++i)
#pragma unroll
    for (int j = 0; j < 4; ++j) {
      int r = row0 + ty + 16*i, o = col0 + tx + 16*j;
      double v = acc[i][j] + (double)bias[o];
      int b = r >> 11, tt = r & (T_SEQ - 1);
      int h = o >> 6, dk = o & 63;
      size_t oi = (((size_t)b * N_HEADS + h) * T_SEQ + tt) * D_HEAD + dk;
      out[oi] = v;
      if (out32) out32[oi] = (float)v;
    }
}

// ---------------------------------------------------------------------------
// Per-row tail with certified bands (mask via bitword).
// ---------------------------------------------------------------------------
__device__ __forceinline__ void process_row(
    const float (&s)[32], int* __restrict__ dkl, float* __restrict__ dwl,
    int* __restrict__ akl, float* __restrict__ awl,
    const double* __restrict__ q64, const double* __restrict__ Kd,
    const float* __restrict__ V, unsigned mw, float* __restrict__ X,
    size_t kvbase, size_t xbase, int lane)
{
  // exact fp32 64th-largest to 256-ulp resolution (mono-key bit search)
  unsigned p = 0u;
  for (int bit = 31; bit >= 8; --bit) {
    unsigned cand = p | (1u << bit);
    float cf = key2f(cand);
    int cnt = 0;
#pragma unroll
    for (int j = 0; j < 32; ++j) cnt += (int)__popcll(__ballot(s[j] >= cf));
    if (cnt >= TOPK_N) p = cand;
  }
  const float pv = key2f(p);          // pv <= v32
  const float pn = key2f(p + 256u);   // v32 < pn
  const float hi = pn + 2.f * EERR;   // s32>=hi  => certainly in f64 top-64
  const float lo = pv - 2.f * EERR;   // s32<lo   => certainly out

  // compact definite list (with weights) and ambiguous list
  int m = 0, na = 0;
#pragma unroll
  for (int j = 0; j < 32; ++j) {
    float sv = s[j];
    bool isd = (sv >= hi);
    bool isa = (sv >= lo) && !isd;
    unsigned long long bd = __ballot(isd);
    unsigned long long ba = __ballot(isa);
    int k = j * 64 + lane;
    if (isd) {
      int pos = m + (int)__popcll(bd & ((1ull << lane) - 1ull));
      if (pos < DCAP) {
        bool msk = ((mw >> j) & 1u) != 0u;
        dkl[pos] = k;
        dwl[pos] = msk ? 0.f : 0.5f * (1.f + erff((sv - LAP_MU_F) * LAP_INV_F));
      }
    }
    if (isa) {
      int pos = na + (int)__popcll(ba & ((1ull << lane) - 1ull));
      if (pos < ACAP) akl[pos] = k;
    }
    m += (int)__popcll(bd);
    na += (int)__popcll(ba);
  }
  if (m > DCAP) m = DCAP;
  if (na > ACAP) na = ACAP;
  const int need = TOPK_N - m;

  // lane-parallel f64 refine of ambiguous candidates (lane e owns akl[e])
  int ke = akl[lane < na ? lane : 0];
  const double* kr = &Kd[kvbase + (size_t)ke * D_HEAD];
  double a0 = 0, a1 = 0, a2 = 0, a3 = 0;
#pragma unroll
  for (int d = 0; d < 64; d += 4) {
    a0 = fma(q64[d + 0], kr[d + 0], a0);
    a1 = fma(q64[d + 1], kr[d + 1], a1);
    a2 = fma(q64[d + 2], kr[d + 2], a2);
    a3 = fma(q64[d + 3], kr[d + 3], a3);
  }
  double s64e = ((a0 + a1) + (a2 + a3)) * 0.125;

  // mask bit for own ambiguous candidate (cross-lane word fetch)
  unsigned mwk = __shfl(mw, ke & 63);
  bool mska = ((mwk >> (ke >> 6)) & 1u) != 0u;

  // rank among A by exact f64 (strict >): rank<need <=> s64 >= vk (ties kept)
  int rank = 0;
  for (int i = 0; i < na; ++i) {
    double vi = __shfl(s64e, i);
    rank += (vi > s64e) ? 1 : 0;
  }
  if (lane < na) {
    bool keep = (rank < need) && !mska;
    awl[lane] = keep ? 0.5f * (1.f + erff(((float)s64e - LAP_MU_F) * LAP_INV_F)) : 0.f;
  }

  // PV: lane owns output dim d=lane
  float acc = 0.f;
  for (int e = 0; e < m; ++e)
    acc = fmaf(dwl[e], V[kvbase + (size_t)dkl[e] * D_HEAD + lane], acc);
  for (int e = 0; e < na; ++e)
    acc = fmaf(awl[e], V[kvbase + (size_t)akl[e] * D_HEAD + lane], acc);
  X[xbase + lane] = acc;
}

// ---------------------------------------------------------------------------
// Fused attention. Block = 256 threads = 4 waves, QROWS=8 (2 rows/wave).
// K staged via global_load_lds with BOTH-SIDES slot swizzle (round-4 pattern).
// q8 f32 LDS staging (round-5 84-VGPR structure).
// ---------------------------------------------------------------------------
__global__ __launch_bounds__(256)
void attn_fused(const double* __restrict__ Qd, const double* __restrict__ Kd,
                const float* __restrict__ K32, const float* __restrict__ V,
                const unsigned* __restrict__ mbits, float* __restrict__ X)
{
  __shared__ float  KsL[512 * 16];       // 32 KB swizzled K chunk
  __shared__ float  q8[QROWS][68];       // 2.1 KB
  __shared__ double q8d[QROWS][64];      // 4 KB
  __shared__ int    dk_l[QROWS][DCAP];
  __shared__ float  dw_l[QROWS][DCAP];
  __shared__ int    ak_l[QROWS][ACAP];
  __shared__ float  aw_l[QROWS][ACAP];

  const int t = threadIdx.x, wv = t >> 6, lane = t & 63;
  const int bh = blockIdx.y, b = bh >> 4, h = bh & 15;
  const int q0 = blockIdx.x * QROWS;
  const size_t kvbase = (size_t)bh * T_SEQ * D_HEAD;

  for (int i = t; i < QROWS * 64; i += 256) {
    int r = i >> 6, d = i & 63;
    double qv = Qd[kvbase + (size_t)(q0 + r) * D_HEAD + d];
    q8d[r][d] = qv;
    q8[r][d] = (float)qv;
  }
  __syncthreads();

  const int r0 = wv * RPW;
  float s0[32], s1[32];
#pragma unroll
  for (int j = 0; j < 32; ++j) { s0[j] = 0.f; s1[j] = 0.f; }

  for (int db = 0; db < 4; ++db) {
    float4 qa[4], qb[4];
#pragma unroll
    for (int qq = 0; qq < 4; ++qq) {
      qa[qq] = *reinterpret_cast<const float4*>(&q8[r0][db * 16 + qq * 4]);
      qb[qq] = *reinterpret_cast<const float4*>(&q8[r0 + 1][db * 16 + qq * 4]);
    }
    for (int kc = 0; kc < 4; ++kc) {
      // stage 512 rows x 16 dims; dest linear, source pre-swizzled:
      // LDS slot (r, s) <- logical quad s ^ ((r>>1)&3)
#pragma unroll
      for (int jj = 0; jj < 8; ++jj) {
        int idx = t + jj * 256;
        int r = idx >> 2, s = idx & 3;
        int dq = s ^ ((r >> 1) & 3);
        const float* gp = &K32[kvbase + (size_t)(kc * 512 + r) * D_HEAD + db * 16 + dq * 4];
        char* lp = (char*)KsL + (size_t)(wv * 64 + jj * 256) * 16;
        __builtin_amdgcn_global_load_lds((const AS1 void*)gp, (AS3 void*)lp, 16, 0, 0);
      }
      __syncthreads();
#pragma unroll
      for (int i = 0; i < 8; ++i) {
        int kr2 = i * 64 + lane;
        int sw = (kr2 >> 1) & 3;
        const float* kp = &KsL[kr2 * 16];
        float4 k0 = *reinterpret_cast<const float4*>(&kp[(0 ^ sw) * 4]);
        float4 k1 = *reinterpret_cast<const float4*>(&kp[(1 ^ sw) * 4]);
        float4 k2 = *reinterpret_cast<const float4*>(&kp[(2 ^ sw) * 4]);
        float4 k3 = *reinterpret_cast<const float4*>(&kp[(3 ^ sw) * 4]);
        int j = kc * 8 + i;
        float a = s0[j], c = s1[j];
        a = fmaf(k0.x, qa[0].x, a); a = fmaf(k0.y, qa[0].y, a);
        a = fmaf(k0.z, qa[0].z, a); a = fmaf(k0.w, qa[0].w, a);
        a = fmaf(k1.x, qa[1].x, a); a = fmaf(k1.y, qa[1].y, a);
        a = fmaf(k1.z, qa[1].z, a); a = fmaf(k1.w, qa[1].w, a);
        a = fmaf(k2.x, qa[2].x, a); a = fmaf(k2.y, qa[2].y, a);
        a = fmaf(k2.z, qa[2].z, a); a = fmaf(k2.w, qa[2].w, a);
        a = fmaf(k3.x, qa[3].x, a); a = fmaf(k3.y, qa[3].y, a);
        a = fmaf(k3.z, qa[3].z, a); a = fmaf(k3.w, qa[3].w, a);
        c = fmaf(k0.x, qb[0].x, c); c = fmaf(k0.y, qb[0].y, c);
        c = fmaf(k0.z, qb[0].z, c); c = fmaf(k0.w, qb[0].w, c);
        c = fmaf(k1.x, qb[1].x, c); c = fmaf(k1.y, qb[1].y, c);
        c = fmaf(k1.z, qb[1].z, c); c = fmaf(k1.w, qb[1].w, c);
        c = fmaf(k2.x, qb[2].x, c); c = fmaf(k2.y, qb[2].y, c);
        c = fmaf(k2.z, qb[2].z, c); c = fmaf(k2.w, qb[2].w, c);
        c = fmaf(k3.x, qb[3].x, c); c = fmaf(k3.y, qb[3].y, c);
        c = fmaf(k3.z, qb[3].z, c); c = fmaf(k3.w, qb[3].w, c);
        s0[j] = a; s1[j] = c;
      }
      __syncthreads();
    }
  }
#pragma unroll
  for (int j = 0; j < 32; ++j) { s0[j] *= 0.125f; s1[j] *= 0.125f; }

  // wave-private tails
  {
    const int lr = r0, qg = q0 + lr;
    const size_t rowg = (size_t)b * T_SEQ + qg;
    unsigned mw = mbits[rowg * 64 + lane];
    process_row(s0, dk_l[lr], dw_l[lr], ak_l[lr], aw_l[lr], q8d[lr],
                Kd, V, mw, X, kvbase,
                rowg * D_MODEL + (size_t)h * D_HEAD, lane);
  }
  {
    const int lr = r0 + 1, qg = q0 + lr;
    const size_t rowg = (size_t)b * T_SEQ + qg;
    unsigned mw = mbits[rowg * 64 + lane];
    process_row(s1, dk_l[lr], dw_l[lr], ak_l[lr], aw_l[lr], q8d[lr],
                Kd, V, mw, X, kvbase,
                rowg * D_MODEL + (size_t)h * D_HEAD, lane);
  }
}

// ---------------------------------------------------------------------------
extern "C" void kernel_launch(void* const* d_in, const int* in_sizes, int n_in,
                              void* d_out, int out_size, void* d_ws, size_t ws_size,
                              hipStream_t stream)
{
  const float* query = (const float*)d_in[0];
  const float* key_  = (const float*)d_in[1];
  const float* value = (const float*)d_in[2];
  const int*   mask  = (const int*)d_in[3];
  const float* wq = (const float*)d_in[4];
  const float* bq = (const float*)d_in[5];
  const float* wk = (const float*)d_in[6];
  const float* bk = (const float*)d_in[7];
  const float* wvp = (const float*)d_in[8];
  const float* bv = (const float*)d_in[9];
  const float* wo = (const float*)d_in[10];
  const float* bo = (const float*)d_in[11];
  float* out = (float*)d_out;

  // ws: Qd f64 32M | Kd f64 32M | Ks32 f32 16M | Xb f32 16M | mbits 1M
  double* Qd   = (double*)d_ws;
  double* Kd   = (double*)((char*)d_ws + ((size_t)32 << 20));
  float*  Ks32 = (float*) ((char*)d_ws + ((size_t)64 << 20));
  float*  Xb   = (float*) ((char*)d_ws + ((size_t)80 << 20));
  unsigned* mbits = (unsigned*)((char*)d_ws + ((size_t)96 << 20));
  float*  Vb   = out;   // V-projection parks in d_out; final GEMM overwrites it

  const int M = N_B * T_SEQ;   // 4096
  hipLaunchKernelGGL(pack_mask, dim3(M / 4), dim3(256), 0, stream, mask, mbits);

  dim3 gg(M / 64, D_MODEL / 64), bb(256);
  hipLaunchKernelGGL(gemm_f64_head, gg, bb, 0, stream, query, wq, bq, Qd, (float*)nullptr, D_MODEL);
  hipLaunchKernelGGL(gemm_f64_head, gg, bb, 0, stream, key_,  wk, bk, Kd, Ks32, D_MODEL);
  hipLaunchKernelGGL(gemm_mfma_f16s, gg, bb, 0, stream, value, wvp, bv, Vb, M, D_MODEL, D_MODEL, 1);

  dim3 ga(T_SEQ / QROWS, N_B * N_HEADS);
  hipLaunchKernelGGL(attn_fused, ga, dim3(256), 0, stream, Qd, Kd, Ks32, Vb, mbits, Xb);

  hipLaunchKernelGGL(gemm_mfma_f16s, gg, bb, 0, stream, Xb, wo, bo, out, M, D_MODEL, D_MODEL, 0);
}

// Round 9
// 1723.719 us; speedup vs baseline: 1.6791x; 1.0950x over previous
//
#include <hip/hip_runtime.h>
#include <math.h>

// Problem constants
#define N_B     2
#define T_SEQ   2048
#define D_MODEL 1024
#define N_HEADS 16
#define D_HEAD  64
#define TOPK_N  64
#define DCAP    80    // definite-in capacity (provably <= 63)
#define ACAP    32    // ambiguous-band capacity (expected 1-3)
#define QROWS   8     // q-rows per block
#define RPW     2     // q-rows per wave

// laplace(x) = 0.5*(1+erf((x-mu)*sqrt(2/pi))), mu=sqrt(.5)
#define LAP_MU_F  0.70710678f
#define LAP_INV_F 0.79788456f
// certified |s_mfma32 - s64| bound (worst-case ~1e-5; 20x margin)
#define EERR      2e-4f

#define AS1 __attribute__((address_space(1)))
#define AS3 __attribute__((address_space(3)))

typedef _Float16 f16x4 __attribute__((ext_vector_type(4)));
typedef _Float16 f16x8 __attribute__((ext_vector_type(8)));
typedef float    f32x4 __attribute__((ext_vector_type(4)));

// decode monotone key back to float
__device__ __forceinline__ float key2f(unsigned k) {
  unsigned b = (k & 0x80000000u) ? (k & 0x7fffffffu) : ~k;
  return __uint_as_float(b);
}

// ---------------------------------------------------------------------------
// mask bit-pack: bits[row][lane] bit j = (mask[row][j*64+lane] != 0)
// ---------------------------------------------------------------------------
__global__ __launch_bounds__(256)
void pack_mask(const int* __restrict__ mask, unsigned* __restrict__ bits)
{
  const int wv = threadIdx.x >> 6, lane = threadIdx.x & 63;
  const int row = blockIdx.x * 4 + wv;             // 0 .. N_B*T_SEQ-1
  const int* mrow = mask + (size_t)row * T_SEQ;
  unsigned w = 0;
#pragma unroll
  for (int j = 0; j < 32; ++j)
    w |= (mrow[j * 64 + lane] != 0 ? 1u : 0u) << j;
  bits[(size_t)row * 64 + lane] = w;
}

// ---------------------------------------------------------------------------
// f16-split MFMA GEMM: out = A @ W^T + bias (validated; bf16-ulp exact)
// ---------------------------------------------------------------------------
__global__ __launch_bounds__(256)
void gemm_mfma_f16s(const float* __restrict__ A, const float* __restrict__ W,
                    const float* __restrict__ bias, float* __restrict__ out,
                    int M, int N, int Kd, int head_layout)
{
  __shared__ _Float16 Ah[64][72], Al[64][72], Bh[64][72], Bl[64][72]; // 36 KB

  const int t = threadIdx.x, lane = t & 63, wv = t >> 6;
  const int row0 = blockIdx.x * 64, col0 = blockIdx.y * 64;
  const int wr = (wv >> 1) * 32, wc = (wv & 1) * 32;
  f32x4 acc[2][2] = {};

  for (int k0 = 0; k0 < Kd; k0 += 64) {
#pragma unroll
    for (int jj = 0; jj < 4; ++jj) {
      int f = t + jj * 256;                 // 0..1023 float4s
      int r = f >> 4, kq = f & 15;
      float4 va = *reinterpret_cast<const float4*>(&A[(size_t)(row0 + r) * Kd + k0 + kq * 4]);
      f16x4 h, l;
      h[0] = (_Float16)va.x; l[0] = (_Float16)(va.x - (float)h[0]);
      h[1] = (_Float16)va.y; l[1] = (_Float16)(va.y - (float)h[1]);
      h[2] = (_Float16)va.z; l[2] = (_Float16)(va.z - (float)h[2]);
      h[3] = (_Float16)va.w; l[3] = (_Float16)(va.w - (float)h[3]);
      *reinterpret_cast<f16x4*>(&Ah[r][kq * 4]) = h;
      *reinterpret_cast<f16x4*>(&Al[r][kq * 4]) = l;
      float4 vw = *reinterpret_cast<const float4*>(&W[(size_t)(col0 + r) * Kd + k0 + kq * 4]);
      vw.x *= 64.f; vw.y *= 64.f; vw.z *= 64.f; vw.w *= 64.f;
      h[0] = (_Float16)vw.x; l[0] = (_Float16)(vw.x - (float)h[0]);
      h[1] = (_Float16)vw.y; l[1] = (_Float16)(vw.y - (float)h[1]);
      h[2] = (_Float16)vw.z; l[2] = (_Float16)(vw.z - (float)h[2]);
      h[3] = (_Float16)vw.w; l[3] = (_Float16)(vw.w - (float)h[3]);
      *reinterpret_cast<f16x4*>(&Bh[r][kq * 4]) = h;
      *reinterpret_cast<f16x4*>(&Bl[r][kq * 4]) = l;
    }
    __syncthreads();

#pragma unroll
    for (int ks = 0; ks < 2; ++ks) {
      const int koff = ks * 32 + (lane >> 4) * 8;
      f16x8 a_h[2], a_l[2], b_h[2], b_l[2];
#pragma unroll
      for (int i = 0; i < 2; ++i) {
        int ar = wr + i * 16 + (lane & 15);
        a_h[i] = *reinterpret_cast<const f16x8*>(&Ah[ar][koff]);
        a_l[i] = *reinterpret_cast<const f16x8*>(&Al[ar][koff]);
        int bc = wc + i * 16 + (lane & 15);
        b_h[i] = *reinterpret_cast<const f16x8*>(&Bh[bc][koff]);
        b_l[i] = *reinterpret_cast<const f16x8*>(&Bl[bc][koff]);
      }
#pragma unroll
      for (int i = 0; i < 2; ++i)
#pragma unroll
        for (int j = 0; j < 2; ++j) {
          acc[i][j] = __builtin_amdgcn_mfma_f32_16x16x32_f16(a_h[i], b_h[j], acc[i][j], 0, 0, 0);
          acc[i][j] = __builtin_amdgcn_mfma_f32_16x16x32_f16(a_l[i], b_h[j], acc[i][j], 0, 0, 0);
          acc[i][j] = __builtin_amdgcn_mfma_f32_16x16x32_f16(a_h[i], b_l[j], acc[i][j], 0, 0, 0);
        }
    }
    __syncthreads();
  }

#pragma unroll
  for (int i = 0; i < 2; ++i)
#pragma unroll
    for (int j = 0; j < 2; ++j)
#pragma unroll
      for (int r = 0; r < 4; ++r) {
        int row = row0 + wr + i * 16 + ((lane >> 4) & 3) * 4 + r;
        int col = col0 + wc + j * 16 + (lane & 15);
        float v = acc[i][j][r] * 0.015625f + bias[col];   // /64 (exact)
        if (head_layout) {
          int b = row >> 11, tt = row & (T_SEQ - 1);
          int hh = col >> 6, dk = col & 63;
          out[(((size_t)b * N_HEADS + hh) * T_SEQ + tt) * D_HEAD + dk] = v;
        } else {
          out[(size_t)row * N + col] = v;
        }
      }
}

// ---------------------------------------------------------------------------
// fp64 GEMM (head layout) for Q,K.  For K, also emits pre-split f16 hi/lo in
// the attn kernel's chunked+swizzled LDS-image layout:
//   per (b,h), chunk c = krow/128: 16 KB region at ((bh*16+c)<<14);
//   byte offset inside = klocal*128 + ((dk*2) ^ ((klocal&7)<<4)).
// So a LINEAR global->LDS copy of a chunk yields the bank-swizzled K tile.
// ---------------------------------------------------------------------------
__global__ __launch_bounds__(256)
void gemm_f64_head(const float* __restrict__ A, const float* __restrict__ W,
                   const float* __restrict__ bias, double* __restrict__ out,
                   char* __restrict__ khS, char* __restrict__ klS, int Kd)
{
  __shared__ double As[64][33];
  __shared__ double Ws[64][33];
  const int t = threadIdx.x;
  const int row0 = blockIdx.x * 64, col0 = blockIdx.y * 64;
  const int ty = t >> 4, tx = t & 15;
  double acc[4][4] = {{0.0}};

  for (int k0 = 0; k0 < Kd; k0 += 32) {
#pragma unroll
    for (int jj = 0; jj < 2; ++jj) {
      int idx = t + jj * 256;
      int r = idx >> 3, kq = idx & 7;
      float4 va = *reinterpret_cast<const float4*>(&A[(size_t)(row0 + r) * Kd + k0 + kq * 4]);
      As[r][kq*4+0] = (double)va.x; As[r][kq*4+1] = (double)va.y;
      As[r][kq*4+2] = (double)va.z; As[r][kq*4+3] = (double)va.w;
      float4 vw = *reinterpret_cast<const float4*>(&W[(size_t)(col0 + r) * Kd + k0 + kq * 4]);
      Ws[r][kq*4+0] = (double)vw.x; Ws[r][kq*4+1] = (double)vw.y;
      Ws[r][kq*4+2] = (double)vw.z; Ws[r][kq*4+3] = (double)vw.w;
    }
    __syncthreads();
#pragma unroll
    for (int kk = 0; kk < 32; ++kk) {
      double a[4], b[4];
#pragma unroll
      for (int i = 0; i < 4; ++i) a[i] = As[ty + 16*i][kk];
#pragma unroll
      for (int j = 0; j < 4; ++j) b[j] = Ws[tx + 16*j][kk];
#pragma unroll
      for (int i = 0; i < 4; ++i)
#pragma unroll
        for (int j = 0; j < 4; ++j) acc[i][j] = fma(a[i], b[j], acc[i][j]);
    }
    __syncthreads();
  }

#pragma unroll
  for (int i = 0; i < 4; ++i)
#pragma unroll
    for (int j = 0; j < 4; ++j) {
      int r = row0 + ty + 16*i, o = col0 + tx + 16*j;
      double v = acc[i][j] + (double)bias[o];
      int b = r >> 11, tt = r & (T_SEQ - 1);
      int h = o >> 6, dk = o & 63;
      size_t oi = (((size_t)b * N_HEADS + h) * T_SEQ + tt) * D_HEAD + dk;
      out[oi] = v;
      if (khS) {
        float f = (float)v;
        _Float16 hh = (_Float16)f;
        _Float16 ll = (_Float16)(f - (float)hh);
        int cch = tt >> 7, klo = tt & 127;
        size_t off = (((size_t)(b * N_HEADS + h) * 16 + cch) << 14)
                   + (size_t)klo * 128 + (size_t)((dk * 2) ^ ((klo & 7) << 4));
        *reinterpret_cast<_Float16*>(khS + off) = hh;
        *reinterpret_cast<_Float16*>(klS + off) = ll;
      }
    }
}

// ---------------------------------------------------------------------------
// Per-row tail with certified bands (mask via bitword) — proven rounds 4-8.
// ---------------------------------------------------------------------------
__device__ __forceinline__ void process_row(
    const float (&s)[32], int* __restrict__ dkl, float* __restrict__ dwl,
    int* __restrict__ akl, float* __restrict__ awl,
    const double* __restrict__ q64, const double* __restrict__ Kd,
    const float* __restrict__ V, unsigned mw, float* __restrict__ X,
    size_t kvbase, size_t xbase, int lane)
{
  // exact fp32 64th-largest to 256-ulp resolution (mono-key bit search)
  unsigned p = 0u;
  for (int bit = 31; bit >= 8; --bit) {
    unsigned cand = p | (1u << bit);
    float cf = key2f(cand);
    int cnt = 0;
#pragma unroll
    for (int j = 0; j < 32; ++j) cnt += (int)__popcll(__ballot(s[j] >= cf));
    if (cnt >= TOPK_N) p = cand;
  }
  const float pv = key2f(p);          // pv <= v32
  const float pn = key2f(p + 256u);   // v32 < pn
  const float hi = pn + 2.f * EERR;   // s32>=hi  => certainly in f64 top-64
  const float lo = pv - 2.f * EERR;   // s32<lo   => certainly out

  // compact definite list (with weights) and ambiguous list
  int m = 0, na = 0;
#pragma unroll
  for (int j = 0; j < 32; ++j) {
    float sv = s[j];
    bool isd = (sv >= hi);
    bool isa = (sv >= lo) && !isd;
    unsigned long long bd = __ballot(isd);
    unsigned long long ba = __ballot(isa);
    int k = j * 64 + lane;
    if (isd) {
      int pos = m + (int)__popcll(bd & ((1ull << lane) - 1ull));
      if (pos < DCAP) {
        bool msk = ((mw >> j) & 1u) != 0u;
        dkl[pos] = k;
        dwl[pos] = msk ? 0.f : 0.5f * (1.f + erff((sv - LAP_MU_F) * LAP_INV_F));
      }
    }
    if (isa) {
      int pos = na + (int)__popcll(ba & ((1ull << lane) - 1ull));
      if (pos < ACAP) akl[pos] = k;
    }
    m += (int)__popcll(bd);
    na += (int)__popcll(ba);
  }
  if (m > DCAP) m = DCAP;
  if (na > ACAP) na = ACAP;
  const int need = TOPK_N - m;

  // lane-parallel f64 refine of ambiguous candidates (lane e owns akl[e])
  int ke = akl[lane < na ? lane : 0];
  const double* kr = &Kd[kvbase + (size_t)ke * D_HEAD];
  double a0 = 0, a1 = 0, a2 = 0, a3 = 0;
#pragma unroll
  for (int d = 0; d < 64; d += 4) {
    a0 = fma(q64[d + 0], kr[d + 0], a0);
    a1 = fma(q64[d + 1], kr[d + 1], a1);
    a2 = fma(q64[d + 2], kr[d + 2], a2);
    a3 = fma(q64[d + 3], kr[d + 3], a3);
  }
  double s64e = ((a0 + a1) + (a2 + a3)) * 0.125;

  // mask bit for own ambiguous candidate (cross-lane word fetch)
  unsigned mwk = __shfl(mw, ke & 63);
  bool mska = ((mwk >> (ke >> 6)) & 1u) != 0u;

  // rank among A by exact f64 (strict >): rank<need <=> s64 >= vk (ties kept)
  int rank = 0;
  for (int i = 0; i < na; ++i) {
    double vi = __shfl(s64e, i);
    rank += (vi > s64e) ? 1 : 0;
  }
  if (lane < na) {
    bool keep = (rank < need) && !mska;
    awl[lane] = keep ? 0.5f * (1.f + erff(((float)s64e - LAP_MU_F) * LAP_INV_F)) : 0.f;
  }

  // PV: lane owns output dim d=lane
  float acc = 0.f;
  for (int e = 0; e < m; ++e)
    acc = fmaf(dwl[e], V[kvbase + (size_t)dkl[e] * D_HEAD + lane], acc);
  for (int e = 0; e < na; ++e)
    acc = fmaf(awl[e], V[kvbase + (size_t)akl[e] * D_HEAD + lane], acc);
  X[xbase + lane] = acc;
}

// ---------------------------------------------------------------------------
// Fused attention, MFMA score phase.
// Block = 4 waves, QROWS=8 q-rows of one (b,h).  K in 16 chunks of 128 rows:
//  - chunk staged (f16 hi+lo, pre-swizzled global image) via global_load_lds
//  - each wave k-partitions (32 rows): 2 tiles x 2 dsteps x 3 split-MFMAs
//    A = K-tile (row=lane&15, k=(lane>>4)*8+j), B = Q (col=lane&15, 8 live)
//  - D (col=q, row=(lane>>4)*4+r) scattered to S_lds[128][9]
//  - each wave reads back its 2 rows into the s0/s1 selection layout
// Tail (pivot/band/refine/PV) unchanged from rounds 4-8.
// ---------------------------------------------------------------------------
__global__ __launch_bounds__(256)
void attn_fused(const double* __restrict__ Qd, const double* __restrict__ Kd,
                const char* __restrict__ KhS, const char* __restrict__ KlS,
                const float* __restrict__ V, const unsigned* __restrict__ mbits,
                float* __restrict__ X)
{
  __shared__ _Float16 KsH[128 * 64];     // 16 KB (swizzled image)
  __shared__ _Float16 KsL[128 * 64];     // 16 KB
  __shared__ float    S_lds[128][9];     // 4.6 KB (pad 9: conflict-free col reads)
  __shared__ _Float16 QhL[QROWS][64];    // 1 KB
  __shared__ _Float16 QlL[QROWS][64];    // 1 KB
  __shared__ double   q8d[QROWS][64];    // 4 KB
  __shared__ int      dk_l[QROWS][DCAP];
  __shared__ float    dw_l[QROWS][DCAP];
  __shared__ int      ak_l[QROWS][ACAP];
  __shared__ float    aw_l[QROWS][ACAP];

  const int t = threadIdx.x, wv = t >> 6, lane = t & 63;
  const int bh = blockIdx.y, b = bh >> 4, h = bh & 15;
  const int q0 = blockIdx.x * QROWS;
  const size_t kvbase = (size_t)bh * T_SEQ * D_HEAD;

  // stage q rows: f64 (for refine) + f16 hi/lo (for MFMA B operand)
  for (int i = t; i < QROWS * 64; i += 256) {
    int r = i >> 6, d = i & 63;
    double qv = Qd[kvbase + (size_t)(q0 + r) * D_HEAD + d];
    q8d[r][d] = qv;
    float qf = (float)qv;
    _Float16 hh = (_Float16)qf;
    QhL[r][d] = hh;
    QlL[r][d] = (_Float16)(qf - (float)hh);
  }
  __syncthreads();

  // hoist Q fragments (per dstep): col=lane&15 (rows 0-7 live), k=(lane>>4)*8+j
  const int qcol = lane & 15, kq = (lane >> 4) * 8;
  f16x8 Bh[2], Bl[2];
#pragma unroll
  for (int ds_ = 0; ds_ < 2; ++ds_) {
    if (qcol < QROWS) {
      Bh[ds_] = *reinterpret_cast<const f16x8*>(&QhL[qcol][ds_ * 32 + kq]);
      Bl[ds_] = *reinterpret_cast<const f16x8*>(&QlL[qcol][ds_ * 32 + kq]);
    } else {
#pragma unroll
      for (int z = 0; z < 8; ++z) { Bh[ds_][z] = (_Float16)0.f; Bl[ds_][z] = (_Float16)0.f; }
    }
  }

  const int r0 = wv * RPW;
  float s0[32], s1[32];
  const size_t chbase = ((size_t)bh * 16) << 14;   // byte base of this bh's chunks

  for (int c = 0; c < 16; ++c) {
    // ---- stage chunk c: linear copy of the pre-swizzled global image ----
    const char* gH = KhS + chbase + ((size_t)c << 14);
    const char* gL = KlS + chbase + ((size_t)c << 14);
#pragma unroll
    for (int jj = 0; jj < 4; ++jj) {
      int idx = t + jj * 256;                       // 0..1023 16B units
      char* lpH = (char*)KsH + (size_t)(wv * 64 + jj * 256) * 16;
      char* lpL = (char*)KsL + (size_t)(wv * 64 + jj * 256) * 16;
      __builtin_amdgcn_global_load_lds((const AS1 void*)(gH + (size_t)idx * 16), (AS3 void*)lpH, 16, 0, 0);
      __builtin_amdgcn_global_load_lds((const AS1 void*)(gL + (size_t)idx * 16), (AS3 void*)lpL, 16, 0, 0);
    }
    __syncthreads();

    // ---- MFMA: wave covers k-rows [wv*32, wv*32+32) of the chunk ----
    f32x4 acc0 = {0.f, 0.f, 0.f, 0.f}, acc1 = {0.f, 0.f, 0.f, 0.f};
    const int rowbase = wv * 32;
#pragma unroll
    for (int tile = 0; tile < 2; ++tile) {
      const int r = rowbase + tile * 16 + (lane & 15);
      f32x4 acc = {0.f, 0.f, 0.f, 0.f};
#pragma unroll
      for (int ds_ = 0; ds_ < 2; ++ds_) {
        int lg = ds_ * 64 + (lane >> 4) * 16;       // logical byte offset in row
        int ph = r * 128 + (lg ^ ((r & 7) << 4));   // swizzled physical byte
        f16x8 Ah = *reinterpret_cast<const f16x8*>((const char*)KsH + ph);
        f16x8 Al = *reinterpret_cast<const f16x8*>((const char*)KsL + ph);
        acc = __builtin_amdgcn_mfma_f32_16x16x32_f16(Ah, Bh[ds_], acc, 0, 0, 0);
        acc = __builtin_amdgcn_mfma_f32_16x16x32_f16(Al, Bh[ds_], acc, 0, 0, 0);
        acc = __builtin_amdgcn_mfma_f32_16x16x32_f16(Ah, Bl[ds_], acc, 0, 0, 0);
      }
      if (tile == 0) acc0 = acc; else acc1 = acc;
    }

    // ---- scatter D to S_lds: row=k-local=(lane>>4)*4+r2, col=q ----
    if (qcol < QROWS) {
#pragma unroll
      for (int r2 = 0; r2 < 4; ++r2) {
        S_lds[rowbase +      (lane >> 4) * 4 + r2][qcol] = acc0[r2];
        S_lds[rowbase + 16 + (lane >> 4) * 4 + r2][qcol] = acc1[r2];
      }
    }
    __syncthreads();

    // ---- gather into selection layout: s[j] = score[k = j*64+lane] ----
    s0[c * 2 + 0] = S_lds[lane][r0]          * 0.125f;
    s0[c * 2 + 1] = S_lds[64 + lane][r0]     * 0.125f;
    s1[c * 2 + 0] = S_lds[lane][r0 + 1]      * 0.125f;
    s1[c * 2 + 1] = S_lds[64 + lane][r0 + 1] * 0.125f;
    // next iteration's stage barrier orders these reads vs next S_lds writes
  }

  // wave-private tails (unchanged)
  {
    const int lr = r0, qg = q0 + lr;
    const size_t rowg = (size_t)b * T_SEQ + qg;
    unsigned mw = mbits[rowg * 64 + lane];
    process_row(s0, dk_l[lr], dw_l[lr], ak_l[lr], aw_l[lr], q8d[lr],
                Kd, V, mw, X, kvbase,
                rowg * D_MODEL + (size_t)h * D_HEAD, lane);
  }
  {
    const int lr = r0 + 1, qg = q0 + lr;
    const size_t rowg = (size_t)b * T_SEQ + qg;
    unsigned mw = mbits[rowg * 64 + lane];
    process_row(s1, dk_l[lr], dw_l[lr], ak_l[lr], aw_l[lr], q8d[lr],
                Kd, V, mw, X, kvbase,
                rowg * D_MODEL + (size_t)h * D_HEAD, lane);
  }
}

// ---------------------------------------------------------------------------
extern "C" void kernel_launch(void* const* d_in, const int* in_sizes, int n_in,
                              void* d_out, int out_size, void* d_ws, size_t ws_size,
                              hipStream_t stream)
{
  const float* query = (const float*)d_in[0];
  const float* key_  = (const float*)d_in[1];
  const float* value = (const float*)d_in[2];
  const int*   mask  = (const int*)d_in[3];
  const float* wq = (const float*)d_in[4];
  const float* bq = (const float*)d_in[5];
  const float* wk = (const float*)d_in[6];
  const float* bk = (const float*)d_in[7];
  const float* wvp = (const float*)d_in[8];
  const float* bv = (const float*)d_in[9];
  const float* wo = (const float*)d_in[10];
  const float* bo = (const float*)d_in[11];
  float* out = (float*)d_out;

  // ws: Qd f64 32M | Kd f64 32M | KhS 8M | KlS 8M | Xb 16M (@80M) | mbits 1M (@96M)
  double* Qd  = (double*)d_ws;
  double* Kd  = (double*)((char*)d_ws + ((size_t)32 << 20));
  char*   KhS = (char*)d_ws + ((size_t)64 << 20);
  char*   KlS = (char*)d_ws + ((size_t)72 << 20);
  float*  Xb  = (float*)((char*)d_ws + ((size_t)80 << 20));
  unsigned* mbits = (unsigned*)((char*)d_ws + ((size_t)96 << 20));
  float*  Vb  = out;   // V-projection parks in d_out; final GEMM overwrites it

  const int M = N_B * T_SEQ;   // 4096
  hipLaunchKernelGGL(pack_mask, dim3(M / 4), dim3(256), 0, stream, mask, mbits);

  dim3 gg(M / 64, D_MODEL / 64), bb(256);
  hipLaunchKernelGGL(gemm_f64_head, gg, bb, 0, stream, query, wq, bq, Qd,
                     (char*)nullptr, (char*)nullptr, D_MODEL);
  hipLaunchKernelGGL(gemm_f64_head, gg, bb, 0, stream, key_,  wk, bk, Kd,
                     KhS, KlS, D_MODEL);
  hipLaunchKernelGGL(gemm_mfma_f16s, gg, bb, 0, stream, value, wvp, bv, Vb, M, D_MODEL, D_MODEL, 1);

  dim3 ga(T_SEQ / QROWS, N_B * N_HEADS);
  hipLaunchKernelGGL(attn_fused, ga, dim3(256), 0, stream, Qd, Kd, KhS, KlS, Vb, mbits, Xb);

  hipLaunchKernelGGL(gemm_mfma_f16s, gg, bb, 0, stream, Xb, wo, bo, out, M, D_MODEL, D_MODEL, 0);
}

// Round 10
// 1573.597 us; speedup vs baseline: 1.8393x; 1.0954x over previous
//
#include <hip/hip_runtime.h>
#include <math.h>

// Problem constants
#define N_B     2
#define T_SEQ   2048
#define D_MODEL 1024
#define N_HEADS 16
#define D_HEAD  64
#define TOPK_N  64
#define DCAP    64    // definite-in capacity (m <= 63 provably)
#define ACAP    32    // ambiguous-band capacity (expected 1-3)
#define QROWS   16    // q-rows per block (full MFMA B operand)
#define RPW     2     // q-rows per wave

// laplace(x) = 0.5*(1+erf((x-mu)*sqrt(2/pi))), mu=sqrt(.5)
#define LAP_MU_F  0.70710678f
#define LAP_INV_F 0.79788456f
// certified |s_mfma32 - s64| bound (worst-case ~1e-5; 20x margin)
#define EERR      2e-4f

#define AS1 __attribute__((address_space(1)))
#define AS3 __attribute__((address_space(3)))

typedef _Float16 f16x4 __attribute__((ext_vector_type(4)));
typedef _Float16 f16x8 __attribute__((ext_vector_type(8)));
typedef float    f32x4 __attribute__((ext_vector_type(4)));

// decode monotone key back to float
__device__ __forceinline__ float key2f(unsigned k) {
  unsigned b = (k & 0x80000000u) ? (k & 0x7fffffffu) : ~k;
  return __uint_as_float(b);
}

// ---------------------------------------------------------------------------
// mask bit-pack: bits[row][lane] bit j = (mask[row][j*64+lane] != 0)
// ---------------------------------------------------------------------------
__global__ __launch_bounds__(256)
void pack_mask(const int* __restrict__ mask, unsigned* __restrict__ bits)
{
  const int wv = threadIdx.x >> 6, lane = threadIdx.x & 63;
  const int row = blockIdx.x * 4 + wv;             // 0 .. N_B*T_SEQ-1
  const int* mrow = mask + (size_t)row * T_SEQ;
  unsigned w = 0;
#pragma unroll
  for (int j = 0; j < 32; ++j)
    w |= (mrow[j * 64 + lane] != 0 ? 1u : 0u) << j;
  bits[(size_t)row * 64 + lane] = w;
}

// ---------------------------------------------------------------------------
// f16-split MFMA GEMM: out = A @ W^T + bias (validated; bf16-ulp exact)
// ---------------------------------------------------------------------------
__global__ __launch_bounds__(256)
void gemm_mfma_f16s(const float* __restrict__ A, const float* __restrict__ W,
                    const float* __restrict__ bias, float* __restrict__ out,
                    int M, int N, int Kd, int head_layout)
{
  __shared__ _Float16 Ah[64][72], Al[64][72], Bh[64][72], Bl[64][72]; // 36 KB

  const int t = threadIdx.x, lane = t & 63, wv = t >> 6;
  const int row0 = blockIdx.x * 64, col0 = blockIdx.y * 64;
  const int wr = (wv >> 1) * 32, wc = (wv & 1) * 32;
  f32x4 acc[2][2] = {};

  for (int k0 = 0; k0 < Kd; k0 += 64) {
#pragma unroll
    for (int jj = 0; jj < 4; ++jj) {
      int f = t + jj * 256;                 // 0..1023 float4s
      int r = f >> 4, kq = f & 15;
      float4 va = *reinterpret_cast<const float4*>(&A[(size_t)(row0 + r) * Kd + k0 + kq * 4]);
      f16x4 h, l;
      h[0] = (_Float16)va.x; l[0] = (_Float16)(va.x - (float)h[0]);
      h[1] = (_Float16)va.y; l[1] = (_Float16)(va.y - (float)h[1]);
      h[2] = (_Float16)va.z; l[2] = (_Float16)(va.z - (float)h[2]);
      h[3] = (_Float16)va.w; l[3] = (_Float16)(va.w - (float)h[3]);
      *reinterpret_cast<f16x4*>(&Ah[r][kq * 4]) = h;
      *reinterpret_cast<f16x4*>(&Al[r][kq * 4]) = l;
      float4 vw = *reinterpret_cast<const float4*>(&W[(size_t)(col0 + r) * Kd + k0 + kq * 4]);
      vw.x *= 64.f; vw.y *= 64.f; vw.z *= 64.f; vw.w *= 64.f;
      h[0] = (_Float16)vw.x; l[0] = (_Float16)(vw.x - (float)h[0]);
      h[1] = (_Float16)vw.y; l[1] = (_Float16)(vw.y - (float)h[1]);
      h[2] = (_Float16)vw.z; l[2] = (_Float16)(vw.z - (float)h[2]);
      h[3] = (_Float16)vw.w; l[3] = (_Float16)(vw.w - (float)h[3]);
      *reinterpret_cast<f16x4*>(&Bh[r][kq * 4]) = h;
      *reinterpret_cast<f16x4*>(&Bl[r][kq * 4]) = l;
    }
    __syncthreads();

#pragma unroll
    for (int ks = 0; ks < 2; ++ks) {
      const int koff = ks * 32 + (lane >> 4) * 8;
      f16x8 a_h[2], a_l[2], b_h[2], b_l[2];
#pragma unroll
      for (int i = 0; i < 2; ++i) {
        int ar = wr + i * 16 + (lane & 15);
        a_h[i] = *reinterpret_cast<const f16x8*>(&Ah[ar][koff]);
        a_l[i] = *reinterpret_cast<const f16x8*>(&Al[ar][koff]);
        int bc = wc + i * 16 + (lane & 15);
        b_h[i] = *reinterpret_cast<const f16x8*>(&Bh[bc][koff]);
        b_l[i] = *reinterpret_cast<const f16x8*>(&Bl[bc][koff]);
      }
#pragma unroll
      for (int i = 0; i < 2; ++i)
#pragma unroll
        for (int j = 0; j < 2; ++j) {
          acc[i][j] = __builtin_amdgcn_mfma_f32_16x16x32_f16(a_h[i], b_h[j], acc[i][j], 0, 0, 0);
          acc[i][j] = __builtin_amdgcn_mfma_f32_16x16x32_f16(a_l[i], b_h[j], acc[i][j], 0, 0, 0);
          acc[i][j] = __builtin_amdgcn_mfma_f32_16x16x32_f16(a_h[i], b_l[j], acc[i][j], 0, 0, 0);
        }
    }
    __syncthreads();
  }

#pragma unroll
  for (int i = 0; i < 2; ++i)
#pragma unroll
    for (int j = 0; j < 2; ++j)
#pragma unroll
      for (int r = 0; r < 4; ++r) {
        int row = row0 + wr + i * 16 + ((lane >> 4) & 3) * 4 + r;
        int col = col0 + wc + j * 16 + (lane & 15);
        float v = acc[i][j][r] * 0.015625f + bias[col];   // /64 (exact)
        if (head_layout) {
          int b = row >> 11, tt = row & (T_SEQ - 1);
          int hh = col >> 6, dk = col & 63;
          out[(((size_t)b * N_HEADS + hh) * T_SEQ + tt) * D_HEAD + dk] = v;
        } else {
          out[(size_t)row * N + col] = v;
        }
      }
}

// ---------------------------------------------------------------------------
// fp64 GEMM (head layout) for Q,K — retiled 64x128, acc 4x8 (DS/FMA 0.375).
// For K, also emits pre-split f16 hi/lo in the attn chunked+swizzled image:
//   byte off = chunk_base + klocal*128 + ((dk*2) ^ ((klocal&7)<<4)).
// ---------------------------------------------------------------------------
__global__ __launch_bounds__(256)
void gemm_f64_head(const float* __restrict__ A, const float* __restrict__ W,
                   const float* __restrict__ bias, double* __restrict__ out,
                   char* __restrict__ khS, char* __restrict__ klS, int Kd)
{
  __shared__ double As[64][33];     // 16.9 KB
  __shared__ double Ws[128][33];    // 33.8 KB
  const int t = threadIdx.x;
  const int row0 = blockIdx.x * 64, col0 = blockIdx.y * 128;
  const int ty = t >> 4, tx = t & 15;
  double acc[4][8] = {{0.0}};

  for (int k0 = 0; k0 < Kd; k0 += 32) {
#pragma unroll
    for (int jj = 0; jj < 2; ++jj) {
      int idx = t + jj * 256;                // 0..511: A tile
      int r = idx >> 3, kq = idx & 7;
      float4 va = *reinterpret_cast<const float4*>(&A[(size_t)(row0 + r) * Kd + k0 + kq * 4]);
      As[r][kq*4+0] = (double)va.x; As[r][kq*4+1] = (double)va.y;
      As[r][kq*4+2] = (double)va.z; As[r][kq*4+3] = (double)va.w;
    }
#pragma unroll
    for (int jj = 0; jj < 4; ++jj) {
      int idx = t + jj * 256;                // 0..1023: W tile (128 rows)
      int r = idx >> 3, kq = idx & 7;
      float4 vw = *reinterpret_cast<const float4*>(&W[(size_t)(col0 + r) * Kd + k0 + kq * 4]);
      Ws[r][kq*4+0] = (double)vw.x; Ws[r][kq*4+1] = (double)vw.y;
      Ws[r][kq*4+2] = (double)vw.z; Ws[r][kq*4+3] = (double)vw.w;
    }
    __syncthreads();
#pragma unroll
    for (int kk = 0; kk < 32; ++kk) {
      double a[4], b[8];
#pragma unroll
      for (int i = 0; i < 4; ++i) a[i] = As[ty + 16*i][kk];
#pragma unroll
      for (int j = 0; j < 8; ++j) b[j] = Ws[tx + 16*j][kk];
#pragma unroll
      for (int i = 0; i < 4; ++i)
#pragma unroll
        for (int j = 0; j < 8; ++j) acc[i][j] = fma(a[i], b[j], acc[i][j]);
    }
    __syncthreads();
  }

#pragma unroll
  for (int i = 0; i < 4; ++i)
#pragma unroll
    for (int j = 0; j < 8; ++j) {
      int r = row0 + ty + 16*i, o = col0 + tx + 16*j;
      double v = acc[i][j] + (double)bias[o];
      int b = r >> 11, tt = r & (T_SEQ - 1);
      int h = o >> 6, dk = o & 63;
      size_t oi = (((size_t)b * N_HEADS + h) * T_SEQ + tt) * D_HEAD + dk;
      out[oi] = v;
      if (khS) {
        float f = (float)v;
        _Float16 hh = (_Float16)f;
        _Float16 ll = (_Float16)(f - (float)hh);
        int cch = tt >> 7, klo = tt & 127;
        size_t off = (((size_t)(b * N_HEADS + h) * 16 + cch) << 14)
                   + (size_t)klo * 128 + (size_t)((dk * 2) ^ ((klo & 7) << 4));
        *reinterpret_cast<_Float16*>(khS + off) = hh;
        *reinterpret_cast<_Float16*>(klS + off) = ll;
      }
    }
}

// ---------------------------------------------------------------------------
// Per-row tail with certified bands (mask via bitword) — proven rounds 4-9.
// PV manually unrolled 4-way (4 outstanding V loads).
// ---------------------------------------------------------------------------
__device__ __forceinline__ void process_row(
    const float (&s)[32], int* __restrict__ dkl, float* __restrict__ dwl,
    int* __restrict__ akl, float* __restrict__ awl,
    const double* __restrict__ q64, const double* __restrict__ Kd,
    const float* __restrict__ V, unsigned mw, float* __restrict__ X,
    size_t kvbase, size_t xbase, int lane)
{
  // exact fp32 64th-largest to 256-ulp resolution (mono-key bit search)
  unsigned p = 0u;
  for (int bit = 31; bit >= 8; --bit) {
    unsigned cand = p | (1u << bit);
    float cf = key2f(cand);
    int cnt = 0;
#pragma unroll
    for (int j = 0; j < 32; ++j) cnt += (int)__popcll(__ballot(s[j] >= cf));
    if (cnt >= TOPK_N) p = cand;
  }
  const float pv = key2f(p);          // pv <= v32
  const float pn = key2f(p + 256u);   // v32 < pn
  const float hi = pn + 2.f * EERR;   // s32>=hi  => certainly in f64 top-64
  const float lo = pv - 2.f * EERR;   // s32<lo   => certainly out

  // compact definite list (with weights) and ambiguous list
  int m = 0, na = 0;
#pragma unroll
  for (int j = 0; j < 32; ++j) {
    float sv = s[j];
    bool isd = (sv >= hi);
    bool isa = (sv >= lo) && !isd;
    unsigned long long bd = __ballot(isd);
    unsigned long long ba = __ballot(isa);
    int k = j * 64 + lane;
    if (isd) {
      int pos = m + (int)__popcll(bd & ((1ull << lane) - 1ull));
      if (pos < DCAP) {
        bool msk = ((mw >> j) & 1u) != 0u;
        dkl[pos] = k;
        dwl[pos] = msk ? 0.f : 0.5f * (1.f + erff((sv - LAP_MU_F) * LAP_INV_F));
      }
    }
    if (isa) {
      int pos = na + (int)__popcll(ba & ((1ull << lane) - 1ull));
      if (pos < ACAP) akl[pos] = k;
    }
    m += (int)__popcll(bd);
    na += (int)__popcll(ba);
  }
  if (m > DCAP) m = DCAP;   // unreachable: m <= 63
  if (na > ACAP) na = ACAP;
  const int need = TOPK_N - m;

  // lane-parallel f64 refine of ambiguous candidates (lane e owns akl[e])
  int ke = akl[lane < na ? lane : 0];
  const double* kr = &Kd[kvbase + (size_t)ke * D_HEAD];
  double a0 = 0, a1 = 0, a2 = 0, a3 = 0;
#pragma unroll
  for (int d = 0; d < 64; d += 4) {
    a0 = fma(q64[d + 0], kr[d + 0], a0);
    a1 = fma(q64[d + 1], kr[d + 1], a1);
    a2 = fma(q64[d + 2], kr[d + 2], a2);
    a3 = fma(q64[d + 3], kr[d + 3], a3);
  }
  double s64e = ((a0 + a1) + (a2 + a3)) * 0.125;

  // mask bit for own ambiguous candidate (cross-lane word fetch)
  unsigned mwk = __shfl(mw, ke & 63);
  bool mska = ((mwk >> (ke >> 6)) & 1u) != 0u;

  // rank among A by exact f64 (strict >): rank<need <=> s64 >= vk (ties kept)
  int rank = 0;
  for (int i = 0; i < na; ++i) {
    double vi = __shfl(s64e, i);
    rank += (vi > s64e) ? 1 : 0;
  }
  if (lane < na) {
    bool keep = (rank < need) && !mska;
    awl[lane] = keep ? 0.5f * (1.f + erff(((float)s64e - LAP_MU_F) * LAP_INV_F)) : 0.f;
  }

  // PV: lane owns output dim d=lane; 4 accumulators -> 4 outstanding loads
  float c0 = 0.f, c1 = 0.f, c2 = 0.f, c3 = 0.f;
  int e = 0;
  for (; e + 4 <= m; e += 4) {
    c0 = fmaf(dwl[e+0], V[kvbase + (size_t)dkl[e+0] * D_HEAD + lane], c0);
    c1 = fmaf(dwl[e+1], V[kvbase + (size_t)dkl[e+1] * D_HEAD + lane], c1);
    c2 = fmaf(dwl[e+2], V[kvbase + (size_t)dkl[e+2] * D_HEAD + lane], c2);
    c3 = fmaf(dwl[e+3], V[kvbase + (size_t)dkl[e+3] * D_HEAD + lane], c3);
  }
  for (; e < m; ++e)
    c0 = fmaf(dwl[e], V[kvbase + (size_t)dkl[e] * D_HEAD + lane], c0);
  for (int e2 = 0; e2 < na; ++e2)
    c1 = fmaf(awl[e2], V[kvbase + (size_t)akl[e2] * D_HEAD + lane], c1);
  X[xbase + lane] = (c0 + c1) + (c2 + c3);
}

// ---------------------------------------------------------------------------
// Fused attention, MFMA score phase. Block = 8 waves (512 thr), QROWS=16.
// K in 16 chunks of 128 rows (f16 hi+lo pre-swizzled global image,
// global_load_lds staged). Each wave owns 16 k-rows per chunk:
//   1 tile x 2 dsteps x 3 split-MFMAs; B = all 16 q-rows (full operand).
// D scattered to S_lds[128][17]; waves gather their 2 rows into s0/s1.
// Tail (pivot/band/refine/PV) proven rounds 4-9.
// ---------------------------------------------------------------------------
__global__ __launch_bounds__(512)
void attn_fused(const double* __restrict__ Qd, const double* __restrict__ Kd,
                const char* __restrict__ KhS, const char* __restrict__ KlS,
                const float* __restrict__ V, const unsigned* __restrict__ mbits,
                float* __restrict__ X)
{
  __shared__ _Float16 KsH[128 * 64];     // 16 KB (swizzled image)
  __shared__ _Float16 KsL[128 * 64];     // 16 KB
  __shared__ float    S_lds[128][17];    // 8.5 KB
  __shared__ _Float16 QhL[QROWS][64];    // 2 KB
  __shared__ _Float16 QlL[QROWS][64];    // 2 KB
  __shared__ double   q8d[QROWS][64];    // 8 KB
  __shared__ int      dk_l[QROWS][DCAP]; // 4 KB
  __shared__ float    dw_l[QROWS][DCAP]; // 4 KB
  __shared__ int      ak_l[QROWS][ACAP]; // 2 KB
  __shared__ float    aw_l[QROWS][ACAP]; // 2 KB

  const int t = threadIdx.x, wv = t >> 6, lane = t & 63;
  const int bh = blockIdx.y, b = bh >> 4, h = bh & 15;
  const int q0 = blockIdx.x * QROWS;
  const size_t kvbase = (size_t)bh * T_SEQ * D_HEAD;

  // stage q rows: f64 (refine) + f16 hi/lo (MFMA B operand)
  for (int i = t; i < QROWS * 64; i += 512) {
    int r = i >> 6, d = i & 63;
    double qv = Qd[kvbase + (size_t)(q0 + r) * D_HEAD + d];
    q8d[r][d] = qv;
    float qf = (float)qv;
    _Float16 hh = (_Float16)qf;
    QhL[r][d] = hh;
    QlL[r][d] = (_Float16)(qf - (float)hh);
  }
  __syncthreads();

  // hoist Q fragments: col=lane&15 (all 16 live), k=(lane>>4)*8+j
  const int qcol = lane & 15, kq = (lane >> 4) * 8;
  f16x8 Bh[2], Bl[2];
#pragma unroll
  for (int ds_ = 0; ds_ < 2; ++ds_) {
    Bh[ds_] = *reinterpret_cast<const f16x8*>(&QhL[qcol][ds_ * 32 + kq]);
    Bl[ds_] = *reinterpret_cast<const f16x8*>(&QlL[qcol][ds_ * 32 + kq]);
  }

  const int r0 = wv * RPW;
  float s0[32], s1[32];
  const size_t chbase = ((size_t)bh * 16) << 14;   // byte base of this bh's chunks

  for (int c = 0; c < 16; ++c) {
    // ---- stage chunk c: linear copy of the pre-swizzled global image ----
    const char* gH = KhS + chbase + ((size_t)c << 14);
    const char* gL = KlS + chbase + ((size_t)c << 14);
#pragma unroll
    for (int jj = 0; jj < 2; ++jj) {
      int base = wv * 64 + jj * 512;                // 16B-unit base for this wave
      char* lpH = (char*)KsH + (size_t)base * 16;
      char* lpL = (char*)KsL + (size_t)base * 16;
      __builtin_amdgcn_global_load_lds((const AS1 void*)(gH + (size_t)(base + lane) * 16), (AS3 void*)lpH, 16, 0, 0);
      __builtin_amdgcn_global_load_lds((const AS1 void*)(gL + (size_t)(base + lane) * 16), (AS3 void*)lpL, 16, 0, 0);
    }
    __syncthreads();

    // ---- MFMA: wave covers k-rows [wv*16, wv*16+16) of the chunk ----
    const int r = wv * 16 + (lane & 15);
    f32x4 acc = {0.f, 0.f, 0.f, 0.f};
#pragma unroll
    for (int ds_ = 0; ds_ < 2; ++ds_) {
      int lg = ds_ * 64 + (lane >> 4) * 16;       // logical byte offset in row
      int ph = r * 128 + (lg ^ ((r & 7) << 4));   // swizzled physical byte
      f16x8 Ah = *reinterpret_cast<const f16x8*>((const char*)KsH + ph);
      f16x8 Al = *reinterpret_cast<const f16x8*>((const char*)KsL + ph);
      acc = __builtin_amdgcn_mfma_f32_16x16x32_f16(Ah, Bh[ds_], acc, 0, 0, 0);
      acc = __builtin_amdgcn_mfma_f32_16x16x32_f16(Al, Bh[ds_], acc, 0, 0, 0);
      acc = __builtin_amdgcn_mfma_f32_16x16x32_f16(Ah, Bl[ds_], acc, 0, 0, 0);
    }

    // ---- scatter D: row = k-local = wv*16 + (lane>>4)*4 + r2, col = q ----
#pragma unroll
    for (int r2 = 0; r2 < 4; ++r2)
      S_lds[wv * 16 + (lane >> 4) * 4 + r2][qcol] = acc[r2];
    __syncthreads();

    // ---- gather into selection layout: s[j] = score[k = j*64+lane] ----
    s0[c * 2 + 0] = S_lds[lane][r0]          * 0.125f;
    s0[c * 2 + 1] = S_lds[64 + lane][r0]     * 0.125f;
    s1[c * 2 + 0] = S_lds[lane][r0 + 1]      * 0.125f;
    s1[c * 2 + 1] = S_lds[64 + lane][r0 + 1] * 0.125f;
    // next iteration's stage barrier orders these reads vs next S_lds writes
  }

  // wave-private tails
  {
    const int lr = r0, qg = q0 + lr;
    const size_t rowg = (size_t)b * T_SEQ + qg;
    unsigned mw = mbits[rowg * 64 + lane];
    process_row(s0, dk_l[lr], dw_l[lr], ak_l[lr], aw_l[lr], q8d[lr],
                Kd, V, mw, X, kvbase,
                rowg * D_MODEL + (size_t)h * D_HEAD, lane);
  }
  {
    const int lr = r0 + 1, qg = q0 + lr;
    const size_t rowg = (size_t)b * T_SEQ + qg;
    unsigned mw = mbits[rowg * 64 + lane];
    process_row(s1, dk_l[lr], dw_l[lr], ak_l[lr], aw_l[lr], q8d[lr],
                Kd, V, mw, X, kvbase,
                rowg * D_MODEL + (size_t)h * D_HEAD, lane);
  }
}

// ---------------------------------------------------------------------------
extern "C" void kernel_launch(void* const* d_in, const int* in_sizes, int n_in,
                              void* d_out, int out_size, void* d_ws, size_t ws_size,
                              hipStream_t stream)
{
  const float* query = (const float*)d_in[0];
  const float* key_  = (const float*)d_in[1];
  const float* value = (const float*)d_in[2];
  const int*   mask  = (const int*)d_in[3];
  const float* wq = (const float*)d_in[4];
  const float* bq = (const float*)d_in[5];
  const float* wk = (const float*)d_in[6];
  const float* bk = (const float*)d_in[7];
  const float* wvp = (const float*)d_in[8];
  const float* bv = (const float*)d_in[9];
  const float* wo = (const float*)d_in[10];
  const float* bo = (const float*)d_in[11];
  float* out = (float*)d_out;

  // ws: Qd f64 32M | Kd f64 32M | KhS 8M | KlS 8M | Xb 16M (@80M) | mbits 1M (@96M)
  double* Qd  = (double*)d_ws;
  double* Kd  = (double*)((char*)d_ws + ((size_t)32 << 20));
  char*   KhS = (char*)d_ws + ((size_t)64 << 20);
  char*   KlS = (char*)d_ws + ((size_t)72 << 20);
  float*  Xb  = (float*)((char*)d_ws + ((size_t)80 << 20));
  unsigned* mbits = (unsigned*)((char*)d_ws + ((size_t)96 << 20));
  float*  Vb  = out;   // V-projection parks in d_out; final GEMM overwrites it

  const int M = N_B * T_SEQ;   // 4096
  hipLaunchKernelGGL(pack_mask, dim3(M / 4), dim3(256), 0, stream, mask, mbits);

  dim3 gg64(M / 64, D_MODEL / 64);
  dim3 gg128(M / 64, D_MODEL / 128);
  hipLaunchKernelGGL(gemm_f64_head, gg128, dim3(256), 0, stream, query, wq, bq, Qd,
                     (char*)nullptr, (char*)nullptr, D_MODEL);
  hipLaunchKernelGGL(gemm_f64_head, gg128, dim3(256), 0, stream, key_,  wk, bk, Kd,
                     KhS, KlS, D_MODEL);
  hipLaunchKernelGGL(gemm_mfma_f16s, gg64, dim3(256), 0, stream, value, wvp, bv, Vb, M, D_MODEL, D_MODEL, 1);

  dim3 ga(T_SEQ / QROWS, N_B * N_HEADS);
  hipLaunchKernelGGL(attn_fused, ga, dim3(512), 0, stream, Qd, Kd, KhS, KlS, Vb, mbits, Xb);

  hipLaunchKernelGGL(gemm_mfma_f16s, gg64, dim3(256), 0, stream, Xb, wo, bo, out, M, D_MODEL, D_MODEL, 0);
}

// Round 11
// 1186.963 us; speedup vs baseline: 2.4384x; 1.3257x over previous
//
#include <hip/hip_runtime.h>
#include <math.h>

// Problem constants
#define N_B     2
#define T_SEQ   2048
#define D_MODEL 1024
#define N_HEADS 16
#define D_HEAD  64
#define TOPK_N  64
#define DCAP    64    // definite-in capacity (m <= 63 provably, EERR-independent)
#define ACAP    40    // ambiguous-band capacity (expected ~9 at EERR=6e-3)
#define QROWS   16    // q-rows per block (full MFMA B operand)
#define RPW     2     // q-rows per wave

// laplace(x) = 0.5*(1+erf((x-mu)*sqrt(2/pi))), mu=sqrt(.5)
#define LAP_MU_F  0.70710678f
#define LAP_INV_F 0.79788456f
// certified |s_bulk - s64| bound for K-hi-only MFMA scores:
// worst-case adversarial-rounding ~9e-4 (Sum|k||q| tail ~31, rel f16 err 2.4e-4, /8)
#define EERR      6e-3f

#define AS1 __attribute__((address_space(1)))
#define AS3 __attribute__((address_space(3)))

typedef _Float16 f16x4 __attribute__((ext_vector_type(4)));
typedef _Float16 f16x8 __attribute__((ext_vector_type(8)));
typedef float    f32x4 __attribute__((ext_vector_type(4)));

// decode monotone key back to float
__device__ __forceinline__ float key2f(unsigned k) {
  unsigned b = (k & 0x80000000u) ? (k & 0x7fffffffu) : ~k;
  return __uint_as_float(b);
}

// ---------------------------------------------------------------------------
// mask bit-pack: bits[row][lane] bit j = (mask[row][j*64+lane] != 0)
// ---------------------------------------------------------------------------
__global__ __launch_bounds__(256)
void pack_mask(const int* __restrict__ mask, unsigned* __restrict__ bits)
{
  const int wv = threadIdx.x >> 6, lane = threadIdx.x & 63;
  const int row = blockIdx.x * 4 + wv;             // 0 .. N_B*T_SEQ-1
  const int* mrow = mask + (size_t)row * T_SEQ;
  unsigned w = 0;
#pragma unroll
  for (int j = 0; j < 32; ++j)
    w |= (mrow[j * 64 + lane] != 0 ? 1u : 0u) << j;
  bits[(size_t)row * 64 + lane] = w;
}

// ---------------------------------------------------------------------------
// f16-split MFMA GEMM: out = A @ W^T + bias (validated; bf16-ulp exact)
// ---------------------------------------------------------------------------
__global__ __launch_bounds__(256)
void gemm_mfma_f16s(const float* __restrict__ A, const float* __restrict__ W,
                    const float* __restrict__ bias, float* __restrict__ out,
                    int M, int N, int Kd, int head_layout)
{
  __shared__ _Float16 Ah[64][72], Al[64][72], Bh[64][72], Bl[64][72]; // 36 KB

  const int t = threadIdx.x, lane = t & 63, wv = t >> 6;
  const int row0 = blockIdx.x * 64, col0 = blockIdx.y * 64;
  const int wr = (wv >> 1) * 32, wc = (wv & 1) * 32;
  f32x4 acc[2][2] = {};

  for (int k0 = 0; k0 < Kd; k0 += 64) {
#pragma unroll
    for (int jj = 0; jj < 4; ++jj) {
      int f = t + jj * 256;                 // 0..1023 float4s
      int r = f >> 4, kq = f & 15;
      float4 va = *reinterpret_cast<const float4*>(&A[(size_t)(row0 + r) * Kd + k0 + kq * 4]);
      f16x4 h, l;
      h[0] = (_Float16)va.x; l[0] = (_Float16)(va.x - (float)h[0]);
      h[1] = (_Float16)va.y; l[1] = (_Float16)(va.y - (float)h[1]);
      h[2] = (_Float16)va.z; l[2] = (_Float16)(va.z - (float)h[2]);
      h[3] = (_Float16)va.w; l[3] = (_Float16)(va.w - (float)h[3]);
      *reinterpret_cast<f16x4*>(&Ah[r][kq * 4]) = h;
      *reinterpret_cast<f16x4*>(&Al[r][kq * 4]) = l;
      float4 vw = *reinterpret_cast<const float4*>(&W[(size_t)(col0 + r) * Kd + k0 + kq * 4]);
      vw.x *= 64.f; vw.y *= 64.f; vw.z *= 64.f; vw.w *= 64.f;
      h[0] = (_Float16)vw.x; l[0] = (_Float16)(vw.x - (float)h[0]);
      h[1] = (_Float16)vw.y; l[1] = (_Float16)(vw.y - (float)h[1]);
      h[2] = (_Float16)vw.z; l[2] = (_Float16)(vw.z - (float)h[2]);
      h[3] = (_Float16)vw.w; l[3] = (_Float16)(vw.w - (float)h[3]);
      *reinterpret_cast<f16x4*>(&Bh[r][kq * 4]) = h;
      *reinterpret_cast<f16x4*>(&Bl[r][kq * 4]) = l;
    }
    __syncthreads();

#pragma unroll
    for (int ks = 0; ks < 2; ++ks) {
      const int koff = ks * 32 + (lane >> 4) * 8;
      f16x8 a_h[2], a_l[2], b_h[2], b_l[2];
#pragma unroll
      for (int i = 0; i < 2; ++i) {
        int ar = wr + i * 16 + (lane & 15);
        a_h[i] = *reinterpret_cast<const f16x8*>(&Ah[ar][koff]);
        a_l[i] = *reinterpret_cast<const f16x8*>(&Al[ar][koff]);
        int bc = wc + i * 16 + (lane & 15);
        b_h[i] = *reinterpret_cast<const f16x8*>(&Bh[bc][koff]);
        b_l[i] = *reinterpret_cast<const f16x8*>(&Bl[bc][koff]);
      }
#pragma unroll
      for (int i = 0; i < 2; ++i)
#pragma unroll
        for (int j = 0; j < 2; ++j) {
          acc[i][j] = __builtin_amdgcn_mfma_f32_16x16x32_f16(a_h[i], b_h[j], acc[i][j], 0, 0, 0);
          acc[i][j] = __builtin_amdgcn_mfma_f32_16x16x32_f16(a_l[i], b_h[j], acc[i][j], 0, 0, 0);
          acc[i][j] = __builtin_amdgcn_mfma_f32_16x16x32_f16(a_h[i], b_l[j], acc[i][j], 0, 0, 0);
        }
    }
    __syncthreads();
  }

#pragma unroll
  for (int i = 0; i < 2; ++i)
#pragma unroll
    for (int j = 0; j < 2; ++j)
#pragma unroll
      for (int r = 0; r < 4; ++r) {
        int row = row0 + wr + i * 16 + ((lane >> 4) & 3) * 4 + r;
        int col = col0 + wc + j * 16 + (lane & 15);
        float v = acc[i][j][r] * 0.015625f + bias[col];   // /64 (exact)
        if (head_layout) {
          int b = row >> 11, tt = row & (T_SEQ - 1);
          int hh = col >> 6, dk = col & 63;
          out[(((size_t)b * N_HEADS + hh) * T_SEQ + tt) * D_HEAD + dk] = v;
        } else {
          out[(size_t)row * N + col] = v;
        }
      }
}

// ---------------------------------------------------------------------------
// fp64 GEMM (head layout) for Q,K — 64x128 tile, acc 4x8.
// For K, also emits pre-split f16 HI in the attn chunked+swizzled image:
//   byte off = ((bh*16 + klocal/128)<<14) + (klocal%128)*128 + ((dk*2)^((klo&7)<<4))
// ---------------------------------------------------------------------------
__global__ __launch_bounds__(256)
void gemm_f64_head(const float* __restrict__ A, const float* __restrict__ W,
                   const float* __restrict__ bias, double* __restrict__ out,
                   char* __restrict__ khS, int Kd)
{
  __shared__ double As[64][33];     // 16.9 KB
  __shared__ double Ws[128][33];    // 33.8 KB
  const int t = threadIdx.x;
  const int row0 = blockIdx.x * 64, col0 = blockIdx.y * 128;
  const int ty = t >> 4, tx = t & 15;
  double acc[4][8] = {{0.0}};

  for (int k0 = 0; k0 < Kd; k0 += 32) {
#pragma unroll
    for (int jj = 0; jj < 2; ++jj) {
      int idx = t + jj * 256;                // 0..511: A tile
      int r = idx >> 3, kq = idx & 7;
      float4 va = *reinterpret_cast<const float4*>(&A[(size_t)(row0 + r) * Kd + k0 + kq * 4]);
      As[r][kq*4+0] = (double)va.x; As[r][kq*4+1] = (double)va.y;
      As[r][kq*4+2] = (double)va.z; As[r][kq*4+3] = (double)va.w;
    }
#pragma unroll
    for (int jj = 0; jj < 4; ++jj) {
      int idx = t + jj * 256;                // 0..1023: W tile (128 rows)
      int r = idx >> 3, kq = idx & 7;
      float4 vw = *reinterpret_cast<const float4*>(&W[(size_t)(col0 + r) * Kd + k0 + kq * 4]);
      Ws[r][kq*4+0] = (double)vw.x; Ws[r][kq*4+1] = (double)vw.y;
      Ws[r][kq*4+2] = (double)vw.z; Ws[r][kq*4+3] = (double)vw.w;
    }
    __syncthreads();
#pragma unroll
    for (int kk = 0; kk < 32; ++kk) {
      double a[4], b[8];
#pragma unroll
      for (int i = 0; i < 4; ++i) a[i] = As[ty + 16*i][kk];
#pragma unroll
      for (int j = 0; j < 8; ++j) b[j] = Ws[tx + 16*j][kk];
#pragma unroll
      for (int i = 0; i < 4; ++i)
#pragma unroll
        for (int j = 0; j < 8; ++j) acc[i][j] = fma(a[i], b[j], acc[i][j]);
    }
    __syncthreads();
  }

#pragma unroll
  for (int i = 0; i < 4; ++i)
#pragma unroll
    for (int j = 0; j < 8; ++j) {
      int r = row0 + ty + 16*i, o = col0 + tx + 16*j;
      double v = acc[i][j] + (double)bias[o];
      int b = r >> 11, tt = r & (T_SEQ - 1);
      int h = o >> 6, dk = o & 63;
      size_t oi = (((size_t)b * N_HEADS + h) * T_SEQ + tt) * D_HEAD + dk;
      out[oi] = v;
      if (khS) {
        _Float16 hh = (_Float16)(float)v;
        int cch = tt >> 7, klo = tt & 127;
        size_t off = (((size_t)(b * N_HEADS + h) * 16 + cch) << 14)
                   + (size_t)klo * 128 + (size_t)((dk * 2) ^ ((klo & 7) << 4));
        *reinterpret_cast<_Float16*>(khS + off) = hh;
      }
    }
}

// ---------------------------------------------------------------------------
// Per-row tail with certified bands (mask via bitword). qrow = global f64 Q
// row (wave-uniform scalar loads). ACAP<=64 so refine is single-pass.
// ---------------------------------------------------------------------------
__device__ __forceinline__ void process_row(
    const float (&s)[32], int* __restrict__ dkl, float* __restrict__ dwl,
    int* __restrict__ akl, float* __restrict__ awl,
    const double* __restrict__ qrow, const double* __restrict__ Kd,
    const float* __restrict__ V, unsigned mw, float* __restrict__ X,
    size_t kvbase, size_t xbase, int lane)
{
  // fp32 64th-largest to 4096-ulp resolution (quant ~1e-3, folded into band)
  unsigned p = 0u;
  for (int bit = 31; bit >= 12; --bit) {
    unsigned cand = p | (1u << bit);
    float cf = key2f(cand);
    int cnt = 0;
#pragma unroll
    for (int j = 0; j < 32; ++j) cnt += (int)__popcll(__ballot(s[j] >= cf));
    if (cnt >= TOPK_N) p = cand;
  }
  const float pv = key2f(p);            // pv <= v32
  const float pn = key2f(p + 4096u);    // v32 < pn
  const float hi = pn + 2.f * EERR;     // s>=hi  => certainly in f64 top-64
  const float lo = pv - 2.f * EERR;     // s<lo   => certainly out

  // compact definite list (with weights) and ambiguous list
  int m = 0, na = 0;
#pragma unroll
  for (int j = 0; j < 32; ++j) {
    float sv = s[j];
    bool isd = (sv >= hi);
    bool isa = (sv >= lo) && !isd;
    unsigned long long bd = __ballot(isd);
    unsigned long long ba = __ballot(isa);
    int k = j * 64 + lane;
    if (isd) {
      int pos = m + (int)__popcll(bd & ((1ull << lane) - 1ull));
      if (pos < DCAP) {
        bool msk = ((mw >> j) & 1u) != 0u;
        dkl[pos] = k;
        dwl[pos] = msk ? 0.f : 0.5f * (1.f + erff((sv - LAP_MU_F) * LAP_INV_F));
      }
    }
    if (isa) {
      int pos = na + (int)__popcll(ba & ((1ull << lane) - 1ull));
      if (pos < ACAP) akl[pos] = k;
    }
    m += (int)__popcll(bd);
    na += (int)__popcll(ba);
  }
  if (m > DCAP) m = DCAP;   // unreachable: m <= 63
  if (na > ACAP) na = ACAP;
  const int need = TOPK_N - m;

  // lane-parallel f64 refine of ambiguous candidates (lane e owns akl[e])
  int ke = (na > 0) ? akl[lane < na ? lane : 0] : 0;
  const double* kr = &Kd[kvbase + (size_t)ke * D_HEAD];
  double a0 = 0, a1 = 0, a2 = 0, a3 = 0;
#pragma unroll
  for (int d = 0; d < 64; d += 4) {
    a0 = fma(qrow[d + 0], kr[d + 0], a0);
    a1 = fma(qrow[d + 1], kr[d + 1], a1);
    a2 = fma(qrow[d + 2], kr[d + 2], a2);
    a3 = fma(qrow[d + 3], kr[d + 3], a3);
  }
  double s64e = ((a0 + a1) + (a2 + a3)) * 0.125;

  // mask bit for own ambiguous candidate (cross-lane word fetch)
  unsigned mwk = __shfl(mw, ke & 63);
  bool mska = ((mwk >> (ke >> 6)) & 1u) != 0u;

  // rank among A by exact f64 (strict >): rank<need <=> s64 >= vk (ties kept)
  int rank = 0;
  for (int i = 0; i < na; ++i) {
    double vi = __shfl(s64e, i);
    rank += (vi > s64e) ? 1 : 0;
  }
  if (lane < na) {
    bool keep = (rank < need) && !mska;
    awl[lane] = keep ? 0.5f * (1.f + erff(((float)s64e - LAP_MU_F) * LAP_INV_F)) : 0.f;
  }

  // PV: lane owns output dim d=lane; 4 accumulators -> 4 outstanding loads
  float c0 = 0.f, c1 = 0.f, c2 = 0.f, c3 = 0.f;
  int e = 0;
  for (; e + 4 <= m; e += 4) {
    c0 = fmaf(dwl[e+0], V[kvbase + (size_t)dkl[e+0] * D_HEAD + lane], c0);
    c1 = fmaf(dwl[e+1], V[kvbase + (size_t)dkl[e+1] * D_HEAD + lane], c1);
    c2 = fmaf(dwl[e+2], V[kvbase + (size_t)dkl[e+2] * D_HEAD + lane], c2);
    c3 = fmaf(dwl[e+3], V[kvbase + (size_t)dkl[e+3] * D_HEAD + lane], c3);
  }
  for (; e < m; ++e)
    c0 = fmaf(dwl[e], V[kvbase + (size_t)dkl[e] * D_HEAD + lane], c0);
  for (int e2 = 0; e2 < na; ++e2)
    c1 = fmaf(awl[e2], V[kvbase + (size_t)akl[e2] * D_HEAD + lane], c1);
  X[xbase + lane] = (c0 + c1) + (c2 + c3);
}

// ---------------------------------------------------------------------------
// Fused attention, pipelined MFMA score phase. Block = 8 waves, QROWS=16.
// K-hi in 16 chunks of 128 rows (pre-swizzled global image). Per chunk:
//   issue stage(c+1) -> MFMA(c) from dbuf -> scatter S_lds dbuf ->
//   __syncthreads (drain overlaps compute) -> gather. ONE barrier per chunk.
// Tail (pivot/band/f64-refine/PV) proven rounds 4-10; EERR widened to 6e-3.
// LDS 62 KB (<64) -> 2 blocks/CU.
// ---------------------------------------------------------------------------
__global__ __launch_bounds__(512)
void attn_fused(const double* __restrict__ Qd, const double* __restrict__ Kd,
                const char* __restrict__ KhS, const float* __restrict__ V,
                const unsigned* __restrict__ mbits, float* __restrict__ X)
{
  __shared__ _Float16 KsH[2][128 * 64];   // 32 KB double-buffered swizzled K
  __shared__ float    S_lds[2][128][17];  // 17 KB double-buffered transpose
  __shared__ char     pool[8192];         // QhL/QlL (prologue) | dk_l/dw_l (tail)
  __shared__ int      ak_l[QROWS][ACAP];  // 2.5 KB
  __shared__ float    aw_l[QROWS][ACAP];  // 2.5 KB

  _Float16 (*QhL)[64] = reinterpret_cast<_Float16(*)[64]>(pool);          // [16][64] 2KB
  _Float16 (*QlL)[64] = reinterpret_cast<_Float16(*)[64]>(pool + 2048);   // [16][64] 2KB
  int      (*dk_l)[DCAP] = reinterpret_cast<int(*)[DCAP]>(pool);          // [16][64] 4KB
  float    (*dw_l)[DCAP] = reinterpret_cast<float(*)[DCAP]>(pool + 4096); // [16][64] 4KB

  const int t = threadIdx.x, wv = t >> 6, lane = t & 63;
  const int bh = blockIdx.y, b = bh >> 4, h = bh & 15;
  const int q0 = blockIdx.x * QROWS;
  const size_t kvbase = (size_t)bh * T_SEQ * D_HEAD;
  const size_t chbase = ((size_t)bh * 16) << 14;   // byte base of this bh's chunks

  // prologue: stage q rows (f16 hi/lo for MFMA B) + chunk 0
  for (int i = t; i < QROWS * 64; i += 512) {
    int r = i >> 6, d = i & 63;
    float qf = (float)Qd[kvbase + (size_t)(q0 + r) * D_HEAD + d];
    _Float16 hh = (_Float16)qf;
    QhL[r][d] = hh;
    QlL[r][d] = (_Float16)(qf - (float)hh);
  }
#pragma unroll
  for (int jj = 0; jj < 2; ++jj) {
    int base = wv * 64 + jj * 512;
    char* lp = (char*)KsH[0] + (size_t)base * 16;
    __builtin_amdgcn_global_load_lds((const AS1 void*)(KhS + chbase + (size_t)(base + lane) * 16),
                                     (AS3 void*)lp, 16, 0, 0);
  }
  __syncthreads();

  // hoist Q fragments: col=lane&15 (all 16 live), k=(lane>>4)*8+j
  const int qcol = lane & 15;
  const int kq = (lane >> 4) * 8;
  f16x8 Bh[2], Bl[2];
#pragma unroll
  for (int ds_ = 0; ds_ < 2; ++ds_) {
    Bh[ds_] = *reinterpret_cast<const f16x8*>(&QhL[qcol][ds_ * 32 + kq]);
    Bl[ds_] = *reinterpret_cast<const f16x8*>(&QlL[qcol][ds_ * 32 + kq]);
  }

  const int r0 = wv * RPW;
  float s0[32], s1[32];

  for (int c = 0; c < 16; ++c) {
    const int cur = c & 1;
    // ---- issue next chunk's stage (latency hides under compute+barrier) ----
    if (c < 15) {
      const char* gH = KhS + chbase + ((size_t)(c + 1) << 14);
#pragma unroll
      for (int jj = 0; jj < 2; ++jj) {
        int base = wv * 64 + jj * 512;
        char* lp = (char*)KsH[cur ^ 1] + (size_t)base * 16;
        __builtin_amdgcn_global_load_lds((const AS1 void*)(gH + (size_t)(base + lane) * 16),
                                         (AS3 void*)lp, 16, 0, 0);
      }
    }

    // ---- MFMA: wave covers k-rows [wv*16, wv*16+16) of chunk c ----
    const int r = wv * 16 + (lane & 15);
    f32x4 acc = {0.f, 0.f, 0.f, 0.f};
#pragma unroll
    for (int ds_ = 0; ds_ < 2; ++ds_) {
      int lg = ds_ * 64 + (lane >> 4) * 16;       // logical byte offset in row
      int ph = r * 128 + (lg ^ ((r & 7) << 4));   // swizzled physical byte
      f16x8 Ah = *reinterpret_cast<const f16x8*>((const char*)KsH[cur] + ph);
      acc = __builtin_amdgcn_mfma_f32_16x16x32_f16(Ah, Bh[ds_], acc, 0, 0, 0);
      acc = __builtin_amdgcn_mfma_f32_16x16x32_f16(Ah, Bl[ds_], acc, 0, 0, 0);
    }

    // ---- scatter D: row = k-local = wv*16 + (lane>>4)*4 + r2, col = q ----
#pragma unroll
    for (int r2 = 0; r2 < 4; ++r2)
      S_lds[cur][wv * 16 + (lane >> 4) * 4 + r2][qcol] = acc[r2];

    __syncthreads();   // orders scatter/gather AND drains next chunk's stage

    // ---- gather into selection layout: s[j] = score[k = j*64+lane] ----
    s0[c * 2 + 0] = S_lds[cur][lane][r0]          * 0.125f;
    s0[c * 2 + 1] = S_lds[cur][64 + lane][r0]     * 0.125f;
    s1[c * 2 + 0] = S_lds[cur][lane][r0 + 1]      * 0.125f;
    s1[c * 2 + 1] = S_lds[cur][64 + lane][r0 + 1] * 0.125f;
    // gather(c) completes before this wave reaches the NEXT barrier; the next
    // scatter targets the other parity -> no race on S_lds[cur].
  }

  // wave-private tails (pool now reused as dk_l/dw_l — Q reads long done)
  {
    const int lr = r0, qg = q0 + lr;
    const size_t rowg = (size_t)b * T_SEQ + qg;
    unsigned mw = mbits[rowg * 64 + lane];
    process_row(s0, dk_l[lr], dw_l[lr], ak_l[lr], aw_l[lr],
                &Qd[kvbase + (size_t)qg * D_HEAD], Kd, V, mw, X, kvbase,
                rowg * D_MODEL + (size_t)h * D_HEAD, lane);
  }
  {
    const int lr = r0 + 1, qg = q0 + lr;
    const size_t rowg = (size_t)b * T_SEQ + qg;
    unsigned mw = mbits[rowg * 64 + lane];
    process_row(s1, dk_l[lr], dw_l[lr], ak_l[lr], aw_l[lr],
                &Qd[kvbase + (size_t)qg * D_HEAD], Kd, V, mw, X, kvbase,
                rowg * D_MODEL + (size_t)h * D_HEAD, lane);
  }
}

// ---------------------------------------------------------------------------
extern "C" void kernel_launch(void* const* d_in, const int* in_sizes, int n_in,
                              void* d_out, int out_size, void* d_ws, size_t ws_size,
                              hipStream_t stream)
{
  const float* query = (const float*)d_in[0];
  const float* key_  = (const float*)d_in[1];
  const float* value = (const float*)d_in[2];
  const int*   mask  = (const int*)d_in[3];
  const float* wq = (const float*)d_in[4];
  const float* bq = (const float*)d_in[5];
  const float* wk = (const float*)d_in[6];
  const float* bk = (const float*)d_in[7];
  const float* wvp = (const float*)d_in[8];
  const float* bv = (const float*)d_in[9];
  const float* wo = (const float*)d_in[10];
  const float* bo = (const float*)d_in[11];
  float* out = (float*)d_out;

  // ws: Qd f64 32M | Kd f64 32M | KhS 8M | Xb 16M (@80M) | mbits 1M (@96M)
  double* Qd  = (double*)d_ws;
  double* Kd  = (double*)((char*)d_ws + ((size_t)32 << 20));
  char*   KhS = (char*)d_ws + ((size_t)64 << 20);
  float*  Xb  = (float*)((char*)d_ws + ((size_t)80 << 20));
  unsigned* mbits = (unsigned*)((char*)d_ws + ((size_t)96 << 20));
  float*  Vb  = out;   // V-projection parks in d_out; final GEMM overwrites it

  const int M = N_B * T_SEQ;   // 4096
  hipLaunchKernelGGL(pack_mask, dim3(M / 4), dim3(256), 0, stream, mask, mbits);

  dim3 gg64(M / 64, D_MODEL / 64);
  dim3 gg128(M / 64, D_MODEL / 128);
  hipLaunchKernelGGL(gemm_f64_head, gg128, dim3(256), 0, stream, query, wq, bq, Qd,
                     (char*)nullptr, D_MODEL);
  hipLaunchKernelGGL(gemm_f64_head, gg128, dim3(256), 0, stream, key_,  wk, bk, Kd,
                     KhS, D_MODEL);
  hipLaunchKernelGGL(gemm_mfma_f16s, gg64, dim3(256), 0, stream, value, wvp, bv, Vb, M, D_MODEL, D_MODEL, 1);

  dim3 ga(T_SEQ / QROWS, N_B * N_HEADS);
  hipLaunchKernelGGL(attn_fused, ga, dim3(512), 0, stream, Qd, Kd, KhS, Vb, mbits, Xb);

  hipLaunchKernelGGL(gemm_mfma_f16s, gg64, dim3(256), 0, stream, Xb, wo, bo, out, M, D_MODEL, D_MODEL, 0);
}